// Round 1
// baseline (965.975 us; speedup 1.0000x reference)
//
#include <hip/hip_runtime.h>
#include <math.h>

// Problem constants (fixed by setup_inputs)
#define NN    20000
#define DEG   16
constexpr int MAXL2 = 1 + DEG;            // 17
constexpr int MAXL1 = MAXL2 + MAXL2*DEG;  // 289
constexpr int MAXL0 = MAXL1*DEG;          // 4624

// ---------------- set construction ----------------

__global__ void k_init(int* m0, int* m1, int* m2,
                       float* lg0, float* lg1, float* lg2, int* cnts) {
    int i = blockIdx.x * 256 + threadIdx.x;
    if (i < NN) {
        m0[i] = 0; m1[i] = 0; m2[i] = 0;
        lg0[i] = 0.f; lg1[i] = 0.f; lg2[i] = 0.f;
    }
    if (i == 0) { cnts[0] = 0; cnts[1] = 0; cnts[2] = 0; cnts[3] = 1; }
}

__global__ void k_seed(const int* __restrict__ senders, int* m2, int* list3) {
    int t = threadIdx.x;
    if (t == 0) { m2[14] = 1; list3[0] = 14; }
    if (t < DEG) m2[senders[14 * DEG + t]] = 1;
}

// mark senders of every marked node (optionally the node itself)
__global__ void k_expand(const int* __restrict__ senders,
                         const int* __restrict__ msrc, int* mdst, int includeSelf) {
    int n = blockIdx.x * 256 + threadIdx.x;
    if (n >= NN) return;
    if (!msrc[n]) return;
    if (includeSelf) mdst[n] = 1;
#pragma unroll
    for (int k = 0; k < DEG; k++) mdst[senders[n * DEG + k]] = 1;
}

__global__ void k_compact(const int* __restrict__ m, int* list, int* inv, int* cnt) {
    int n = blockIdx.x * 256 + threadIdx.x;
    if (n >= NN) return;
    if (m[n]) {
        int p = atomicAdd(cnt, 1);
        list[p] = n;
        if (inv) inv[n] = p;
    }
}

// ---------------- logits: logits[node] += sum_c relu(H[row]@AW)[c]*aq[c] ----------------
// Tiled 64x64 fp32 GEMM, fused relu * aq row-reduction, atomicAdd per row per col-block.

__global__ __launch_bounds__(256)
void k_logits(const float* __restrict__ H, const float* __restrict__ AW,
              const float* __restrict__ aq, float* __restrict__ logits,
              const int* __restrict__ list, const int* __restrict__ cnt,
              int K, int NC, int indexByList) {
    __shared__ float As[64][17];
    __shared__ float Bs[16][64];
    __shared__ float rowsum[64];
    int rcnt = *cnt;
    int row0 = blockIdx.x * 64;
    if (row0 >= rcnt) return;
    int col0 = blockIdx.y * 64;
    int t = threadIdx.x;
    int ty = t >> 4, tx = t & 15;
    float acc[4][4] = {};

    int lr = t >> 2;            // A-load row (0..63)
    int lc = (t & 3) * 4;       // A-load col (0,4,8,12)
    for (int k0 = 0; k0 < K; k0 += 16) {
        {
            int grow = row0 + lr;
            float4 v = make_float4(0.f, 0.f, 0.f, 0.f);
            if (grow < rcnt) {
                int node = list[grow];
                int hrow = indexByList ? node : grow;
                v = *(const float4*)(H + (size_t)hrow * K + k0 + lc);
            }
            As[lr][lc] = v.x; As[lr][lc+1] = v.y; As[lr][lc+2] = v.z; As[lr][lc+3] = v.w;
        }
        for (int kk = t >> 6; kk < 16; kk += 4)
            Bs[kk][t & 63] = AW[(size_t)(k0 + kk) * NC + col0 + (t & 63)];
        __syncthreads();
#pragma unroll
        for (int kk = 0; kk < 16; kk++) {
            float a[4], b[4];
#pragma unroll
            for (int i = 0; i < 4; i++) a[i] = As[ty*4+i][kk];
#pragma unroll
            for (int j = 0; j < 4; j++) b[j] = Bs[kk][tx*4+j];
#pragma unroll
            for (int i = 0; i < 4; i++)
#pragma unroll
                for (int j = 0; j < 4; j++) acc[i][j] += a[i] * b[j];
        }
        __syncthreads();
    }

    if (t < 64) rowsum[t] = 0.f;
    __syncthreads();
    float aqv[4];
#pragma unroll
    for (int j = 0; j < 4; j++) aqv[j] = aq[col0 + tx*4 + j];
#pragma unroll
    for (int i = 0; i < 4; i++) {
        float s = 0.f;
#pragma unroll
        for (int j = 0; j < 4; j++) {
            float v = acc[i][j];
            v = v > 0.f ? v : 0.f;
            s += v * aqv[j];
        }
        atomicAdd(&rowsum[ty*4+i], s);
    }
    __syncthreads();
    if (t < 64) {
        int grow = row0 + t;
        if (grow < rcnt) atomicAdd(&logits[list[grow]], rowsum[t]);
    }
}

// ---------------- attention aggregate ----------------
// For each node in listN: softmax over its 16 senders' logits, weighted sum of source rows.

__global__ __launch_bounds__(256)
void k_agg(const float* __restrict__ Hsrc, const int* __restrict__ inv,
           const float* __restrict__ logits, const int* __restrict__ senders,
           const int* __restrict__ listN, const int* __restrict__ cntN,
           float* __restrict__ hN, int din) {
    __shared__ int   s_row[DEG];
    __shared__ float s_w[DEG];
    __shared__ float s_scale;
    int b = blockIdx.x;
    if (b >= *cntN) return;
    int n = listN[b];
    int t = threadIdx.x;
    if (t < DEG) {
        int s = senders[n * DEG + t];
        s_row[t] = inv ? inv[s] : s;
        s_w[t] = logits[s];
    }
    __syncthreads();
    if (t == 0) {
        float m = -1e30f;
        for (int k = 0; k < DEG; k++) m = fmaxf(m, s_w[k]);
        float d = 0.f;
        for (int k = 0; k < DEG; k++) { float w = expf(s_w[k] - m); s_w[k] = w; d += w; }
        s_scale = 1.f / d;
    }
    __syncthreads();
    float scale = s_scale;
    for (int dI = t; dI < din; dI += 256) {
        float acc = 0.f;
#pragma unroll
        for (int k = 0; k < DEG; k++)
            acc += s_w[k] * Hsrc[(size_t)s_row[k] * din + dI];
        hN[(size_t)b * din + dI] = acc * scale;
    }
}

// ---------------- layer GEMM: Hout = relu(concat(H1[node], A2[row]) @ LW + LB) ----------------

__global__ __launch_bounds__(256)
void k_gemm(const float* __restrict__ H1, const int* __restrict__ inv,
            const float* __restrict__ A2,
            const float* __restrict__ LW, const float* __restrict__ LB,
            const int* __restrict__ listN, const int* __restrict__ cntN,
            float* __restrict__ Hout, int K1, int K2, int NC) {
    __shared__ float As[64][17];
    __shared__ float Bs[16][64];
    int rcnt = *cntN;
    int row0 = blockIdx.x * 64;
    if (row0 >= rcnt) return;
    int col0 = blockIdx.y * 64;
    int t = threadIdx.x;
    int ty = t >> 4, tx = t & 15;
    float acc[4][4] = {};
    int K = K1 + K2;

    int lr = t >> 2;
    int lc = (t & 3) * 4;
    for (int k0 = 0; k0 < K; k0 += 16) {
        {
            int grow = row0 + lr;
            float4 v = make_float4(0.f, 0.f, 0.f, 0.f);
            if (grow < rcnt) {
                int kk = k0 + lc;
                if (kk < K1) {
                    int node = listN[grow];
                    int hrow = inv ? inv[node] : node;
                    v = *(const float4*)(H1 + (size_t)hrow * K1 + kk);
                } else {
                    v = *(const float4*)(A2 + (size_t)grow * K2 + (kk - K1));
                }
            }
            As[lr][lc] = v.x; As[lr][lc+1] = v.y; As[lr][lc+2] = v.z; As[lr][lc+3] = v.w;
        }
        for (int kk = t >> 6; kk < 16; kk += 4)
            Bs[kk][t & 63] = LW[(size_t)(k0 + kk) * NC + col0 + (t & 63)];
        __syncthreads();
#pragma unroll
        for (int kk = 0; kk < 16; kk++) {
            float a[4], b[4];
#pragma unroll
            for (int i = 0; i < 4; i++) a[i] = As[ty*4+i][kk];
#pragma unroll
            for (int j = 0; j < 4; j++) b[j] = Bs[kk][tx*4+j];
#pragma unroll
            for (int i = 0; i < 4; i++)
#pragma unroll
                for (int j = 0; j < 4; j++) acc[i][j] += a[i] * b[j];
        }
        __syncthreads();
    }

#pragma unroll
    for (int i = 0; i < 4; i++) {
        int grow = row0 + ty*4 + i;
        if (grow < rcnt) {
#pragma unroll
            for (int j = 0; j < 4; j++) {
                int c = col0 + tx*4 + j;
                float v = acc[i][j] + LB[c];
                v = v > 0.f ? v : 0.f;
                Hout[(size_t)grow * NC + c] = v;
            }
        }
    }
}

// ---------------- final projection: out = h3 @ ow + ob ----------------

__global__ void k_out(const float* __restrict__ h3, const float* __restrict__ OW,
                      const float* __restrict__ OB, float* __restrict__ out) {
    int j = threadIdx.x;  // 128
    float acc = OB[j];
    for (int k = 0; k < 128; k++) acc += h3[k] * OW[k * 128 + j];
    out[j] = acc;
}

// ---------------- launch ----------------

extern "C" void kernel_launch(void* const* d_in, const int* in_sizes, int n_in,
                              void* d_out, int out_size, void* d_ws, size_t ws_size,
                              hipStream_t stream) {
    const float* X       = (const float*)d_in[0];
    const int*   senders = (const int*)d_in[1];
    // d_in[2] = receivers: known to be repeat(arange(N), DEG); unused.
    const float* lw0 = (const float*)d_in[3];
    const float* lb0 = (const float*)d_in[4];
    const float* aw0 = (const float*)d_in[5];
    const float* aq0 = (const float*)d_in[6];
    const float* lw1 = (const float*)d_in[7];
    const float* lb1 = (const float*)d_in[8];
    const float* aw1 = (const float*)d_in[9];
    const float* aq1 = (const float*)d_in[10];
    const float* lw2 = (const float*)d_in[11];
    const float* lb2 = (const float*)d_in[12];
    const float* aw2 = (const float*)d_in[13];
    const float* aq2 = (const float*)d_in[14];
    const float* owp = (const float*)d_in[15];
    const float* obp = (const float*)d_in[16];
    float* out = (float*)d_out;

    char* ws = (char*)d_ws;
    size_t off = 0;
    auto alloc = [&](size_t nbytes) -> void* {
        void* p = ws + off;
        off += (nbytes + 255) & ~(size_t)255;
        return p;
    };
    int* m0    = (int*)alloc(NN * 4);
    int* m1    = (int*)alloc(NN * 4);
    int* m2    = (int*)alloc(NN * 4);
    int* inv1  = (int*)alloc(NN * 4);
    int* inv2  = (int*)alloc(NN * 4);
    int* list0 = (int*)alloc(MAXL0 * 4);
    int* list1 = (int*)alloc(MAXL1 * 4);
    int* list2 = (int*)alloc(MAXL2 * 4);
    int* list3 = (int*)alloc(4);
    int* cnts  = (int*)alloc(4 * 4);  // cnt0, cnt1, cnt2, cnt3
    float* lg0  = (float*)alloc(NN * 4);
    float* lg1  = (float*)alloc(NN * 4);
    float* lg2  = (float*)alloc(NN * 4);
    float* hN0c = (float*)alloc((size_t)MAXL1 * 1024 * 4);
    float* h1c  = (float*)alloc((size_t)MAXL1 * 512 * 4);
    float* hN1c = (float*)alloc((size_t)MAXL2 * 512 * 4);
    float* h2c  = (float*)alloc((size_t)MAXL2 * 256 * 4);
    float* hN2c = (float*)alloc(256 * 4);
    float* h3c  = (float*)alloc(128 * 4);
    (void)in_sizes; (void)n_in; (void)out_size; (void)ws_size;

    int nblk = (NN + 255) / 256;

    hipLaunchKernelGGL(k_init, dim3(nblk), dim3(256), 0, stream, m0, m1, m2, lg0, lg1, lg2, cnts);
    hipLaunchKernelGGL(k_seed, dim3(1), dim3(64), 0, stream, senders, m2, list3);
    hipLaunchKernelGGL(k_expand, dim3(nblk), dim3(256), 0, stream, senders, m2, m1, 1);
    hipLaunchKernelGGL(k_expand, dim3(nblk), dim3(256), 0, stream, senders, m1, m0, 0);
    hipLaunchKernelGGL(k_compact, dim3(nblk), dim3(256), 0, stream, m2, list2, inv2, cnts + 2);
    hipLaunchKernelGGL(k_compact, dim3(nblk), dim3(256), 0, stream, m1, list1, inv1, cnts + 1);
    hipLaunchKernelGGL(k_compact, dim3(nblk), dim3(256), 0, stream, m0, list0, (int*)nullptr, cnts + 0);

    // ---- layer 0 (din=1024, dh=512) ----
    hipLaunchKernelGGL(k_logits, dim3((MAXL0 + 63) / 64, 512 / 64), dim3(256), 0, stream,
                       X, aw0, aq0, lg0, list0, cnts + 0, 1024, 512, 1);
    hipLaunchKernelGGL(k_agg, dim3(MAXL1), dim3(256), 0, stream,
                       X, (const int*)nullptr, lg0, senders, list1, cnts + 1, hN0c, 1024);
    hipLaunchKernelGGL(k_gemm, dim3((MAXL1 + 63) / 64, 512 / 64), dim3(256), 0, stream,
                       X, (const int*)nullptr, hN0c, lw0, lb0, list1, cnts + 1, h1c, 1024, 1024, 512);

    // ---- layer 1 (din=512, dh=256) ----
    hipLaunchKernelGGL(k_logits, dim3((MAXL1 + 63) / 64, 256 / 64), dim3(256), 0, stream,
                       h1c, aw1, aq1, lg1, list1, cnts + 1, 512, 256, 0);
    hipLaunchKernelGGL(k_agg, dim3(MAXL2), dim3(256), 0, stream,
                       h1c, inv1, lg1, senders, list2, cnts + 2, hN1c, 512);
    hipLaunchKernelGGL(k_gemm, dim3(1, 256 / 64), dim3(256), 0, stream,
                       h1c, inv1, hN1c, lw1, lb1, list2, cnts + 2, h2c, 512, 512, 256);

    // ---- layer 2 (din=256, dh=128) ----
    hipLaunchKernelGGL(k_logits, dim3(1, 128 / 64), dim3(256), 0, stream,
                       h2c, aw2, aq2, lg2, list2, cnts + 2, 256, 128, 0);
    hipLaunchKernelGGL(k_agg, dim3(1), dim3(256), 0, stream,
                       h2c, inv2, lg2, senders, list3, cnts + 3, hN2c, 256);
    hipLaunchKernelGGL(k_gemm, dim3(1, 128 / 64), dim3(256), 0, stream,
                       h2c, inv2, hN2c, lw2, lb2, list3, cnts + 3, h3c, 256, 256, 128);

    // ---- output ----
    hipLaunchKernelGGL(k_out, dim3(1), dim3(128), 0, stream, h3c, owp, obp, out);
}

// Round 2
// 345.855 us; speedup vs baseline: 2.7930x; 2.7930x over previous
//
#include <hip/hip_runtime.h>
#include <math.h>

// Problem constants (fixed by setup_inputs)
#define NN    20000
#define DEG   16
constexpr int MAXL2 = 1 + DEG;            // 17
constexpr int MAXL1 = MAXL2 + MAXL2*DEG;  // 289
constexpr int MAXL0 = MAXL1*DEG;          // 4624

// ---------------- zero + set construction ----------------

__global__ void k_zero(float4* p, int n4) {
    int i = blockIdx.x * 256 + threadIdx.x;
    if (i < n4) p[i] = make_float4(0.f, 0.f, 0.f, 0.f);
}

__global__ void k_seed(const int* __restrict__ senders, int* m2, int* list3, int* cnts) {
    int t = threadIdx.x;
    if (t == 0) { m2[14] = 1; list3[0] = 14; cnts[3] = 1; }
    if (t < DEG) m2[senders[14 * DEG + t]] = 1;
}

// mark senders of every marked node (optionally the node itself)
__global__ void k_expand(const int* __restrict__ senders,
                         const int* __restrict__ msrc, int* mdst, int includeSelf) {
    int n = blockIdx.x * 256 + threadIdx.x;
    if (n >= NN) return;
    if (!msrc[n]) return;
    if (includeSelf) mdst[n] = 1;
#pragma unroll
    for (int k = 0; k < DEG; k++) mdst[senders[n * DEG + k]] = 1;
}

__global__ void k_compact(const int* __restrict__ m, int* list, int* inv, int* cnt) {
    int n = blockIdx.x * 256 + threadIdx.x;
    if (n >= NN) return;
    if (m[n]) {
        int p = atomicAdd(cnt, 1);
        list[p] = n;
        if (inv) inv[n] = p;
    }
}

// ---------------- generic pipelined GEMM ----------------
// 64x64 tile, BK=32, register-prefetch software pipeline (1 LDS buffer).
// A = concat(A1-rows, A2-rows) per amode; B row-major [K x NC].
// omode 0: C[r*NC+c] += acc  (atomic, split-K via blockIdx.z, KS = K-slice)
// omode 1: logits[list[r]] += sum_c relu(acc[r][c]) * aq[c]   (requires ksplit==1)

__global__ __launch_bounds__(256)
void k_matmul(const float* __restrict__ A1, const float* __restrict__ A2,
              const int* __restrict__ list, const int* __restrict__ inv,
              const float* __restrict__ B, const float* __restrict__ aq,
              float* __restrict__ C, const int* __restrict__ cnt,
              int amode, int omode, int K1, int K2, int NC, int KS) {
    __shared__ float As[32][68];   // transposed: As[k][row], pad 68 for 16B-aligned rows
    __shared__ float Bs[32][64];
    __shared__ float rowsum[64];

    int rcnt = *cnt;
    int row0 = blockIdx.x * 64;
    if (row0 >= rcnt) return;
    int col0 = blockIdx.y * 64;
    int K = K1 + K2;
    int kbeg = blockIdx.z * KS;
    int kend = kbeg + KS; if (kend > K) kend = K;

    int t = threadIdx.x;
    int ty = t >> 4, tx = t & 15;

    // ---- loader setup ----
    int lr = t >> 2;                 // A-load row within tile (0..63)
    int kaoff = (t & 3) * 4;         // A-load k offset within BK (0,4,8,12)
    int grow = row0 + lr;
    bool rowValid = grow < rcnt;
    const float* rp1 = A1;
    const float* rp2 = A2;
    if (rowValid) {
        int hrow;
        if (amode == 0) hrow = grow;
        else { int node = list[grow]; hrow = (amode == 2) ? inv[node] : node; }
        rp1 = A1 + (size_t)hrow * K1;
        rp2 = A2 + (size_t)grow * K2;
    }
    const float* Bp = B + col0;
    int bidx0 = t, bidx1 = t + 256;  // B-tile float4 indices (512 total)

    auto loadA = [&](int k) -> float4 {
        if (!rowValid) return make_float4(0.f, 0.f, 0.f, 0.f);
        const float* src = (k < K1) ? (rp1 + k) : (rp2 + (k - K1));
        return *(const float4*)src;
    };
    auto loadB = [&](int idx, int k0) -> float4 {
        int row = idx >> 4, c4 = (idx & 15) * 4;
        return *(const float4*)(Bp + (size_t)(k0 + row) * NC + c4);
    };

    float4 pa0 = loadA(kbeg + kaoff);
    float4 pa1 = loadA(kbeg + kaoff + 16);
    float4 pb0 = loadB(bidx0, kbeg);
    float4 pb1 = loadB(bidx1, kbeg);

    float acc[4][4] = {};
    for (int k0 = kbeg; k0 < kend; k0 += 32) {
        // store prefetched tile to LDS
        As[kaoff + 0][lr] = pa0.x; As[kaoff + 1][lr] = pa0.y;
        As[kaoff + 2][lr] = pa0.z; As[kaoff + 3][lr] = pa0.w;
        As[kaoff + 16][lr] = pa1.x; As[kaoff + 17][lr] = pa1.y;
        As[kaoff + 18][lr] = pa1.z; As[kaoff + 19][lr] = pa1.w;
        *(float4*)&Bs[bidx0 >> 4][(bidx0 & 15) * 4] = pb0;
        *(float4*)&Bs[bidx1 >> 4][(bidx1 & 15) * 4] = pb1;
        __syncthreads();
        if (k0 + 32 < kend) {       // issue next-tile loads; latency hides under compute
            pa0 = loadA(k0 + 32 + kaoff);
            pa1 = loadA(k0 + 32 + kaoff + 16);
            pb0 = loadB(bidx0, k0 + 32);
            pb1 = loadB(bidx1, k0 + 32);
        }
#pragma unroll
        for (int kk = 0; kk < 32; kk++) {
            float4 a4 = *(const float4*)&As[kk][ty * 4];
            float4 b4 = *(const float4*)&Bs[kk][tx * 4];
            float a[4] = {a4.x, a4.y, a4.z, a4.w};
            float b[4] = {b4.x, b4.y, b4.z, b4.w};
#pragma unroll
            for (int i = 0; i < 4; i++)
#pragma unroll
                for (int j = 0; j < 4; j++) acc[i][j] += a[i] * b[j];
        }
        __syncthreads();
    }

    if (omode == 0) {
#pragma unroll
        for (int i = 0; i < 4; i++) {
            int r = row0 + ty * 4 + i;
            if (r < rcnt) {
                float* Crow = C + (size_t)r * NC + col0 + tx * 4;
#pragma unroll
                for (int j = 0; j < 4; j++) atomicAdd(&Crow[j], acc[i][j]);
            }
        }
    } else {
        if (t < 64) rowsum[t] = 0.f;
        __syncthreads();
        float aqv[4];
#pragma unroll
        for (int j = 0; j < 4; j++) aqv[j] = aq[col0 + tx * 4 + j];
#pragma unroll
        for (int i = 0; i < 4; i++) {
            float s = 0.f;
#pragma unroll
            for (int j = 0; j < 4; j++) {
                float v = acc[i][j];
                v = v > 0.f ? v : 0.f;
                s += v * aqv[j];
            }
            atomicAdd(&rowsum[ty * 4 + i], s);
        }
        __syncthreads();
        if (t < 64) {
            int r = row0 + t;
            if (r < rcnt) atomicAdd(&C[list[r]], rowsum[t]);
        }
    }
}

// ---------------- bias + relu epilogue: H = relu(C + b) ----------------

__global__ void k_bias_relu(const float* __restrict__ C, const float* __restrict__ b,
                            float* __restrict__ H, const int* __restrict__ cnt,
                            int ncShift) {
    int rcnt = *cnt;
    int NC = 1 << ncShift;
    int e = blockIdx.x * 256 + threadIdx.x;
    int r = e >> ncShift;
    if (r >= rcnt) return;
    int c = e & (NC - 1);
    float v = C[(size_t)r * NC + c] + b[c];
    H[(size_t)r * NC + c] = v > 0.f ? v : 0.f;
}

// ---------------- attention aggregate ----------------

__global__ __launch_bounds__(256)
void k_agg(const float* __restrict__ Hsrc, const int* __restrict__ inv,
           const float* __restrict__ logits, const int* __restrict__ senders,
           const int* __restrict__ listN, const int* __restrict__ cntN,
           float* __restrict__ hN, int din) {
    __shared__ int   s_row[DEG];
    __shared__ float s_w[DEG];
    __shared__ float s_scale;
    int b = blockIdx.x;
    if (b >= *cntN) return;
    int n = listN[b];
    int t = threadIdx.x;
    if (t < DEG) {
        int s = senders[n * DEG + t];
        s_row[t] = inv ? inv[s] : s;
        s_w[t] = logits[s];
    }
    __syncthreads();
    if (t == 0) {
        float m = -1e30f;
        for (int k = 0; k < DEG; k++) m = fmaxf(m, s_w[k]);
        float d = 0.f;
        for (int k = 0; k < DEG; k++) { float w = expf(s_w[k] - m); s_w[k] = w; d += w; }
        s_scale = 1.f / d;
    }
    __syncthreads();
    float scale = s_scale;
    for (int dI = t; dI < din; dI += 256) {
        float acc = 0.f;
#pragma unroll
        for (int k = 0; k < DEG; k++)
            acc += s_w[k] * Hsrc[(size_t)s_row[k] * din + dI];
        hN[(size_t)b * din + dI] = acc * scale;
    }
}

// ---------------- final projection: out = h3 @ ow + ob ----------------

__global__ void k_out(const float* __restrict__ h3, const float* __restrict__ OW,
                      const float* __restrict__ OB, float* __restrict__ out) {
    int j = threadIdx.x;  // 128
    float acc = OB[j];
    for (int k = 0; k < 128; k++) acc += h3[k] * OW[k * 128 + j];
    out[j] = acc;
}

// ---------------- launch ----------------

extern "C" void kernel_launch(void* const* d_in, const int* in_sizes, int n_in,
                              void* d_out, int out_size, void* d_ws, size_t ws_size,
                              hipStream_t stream) {
    const float* X       = (const float*)d_in[0];
    const int*   senders = (const int*)d_in[1];
    // d_in[2] = receivers: repeat(arange(N), DEG); unused.
    const float* lw0 = (const float*)d_in[3];
    const float* lb0 = (const float*)d_in[4];
    const float* aw0 = (const float*)d_in[5];
    const float* aq0 = (const float*)d_in[6];
    const float* lw1 = (const float*)d_in[7];
    const float* lb1 = (const float*)d_in[8];
    const float* aw1 = (const float*)d_in[9];
    const float* aq1 = (const float*)d_in[10];
    const float* lw2 = (const float*)d_in[11];
    const float* lb2 = (const float*)d_in[12];
    const float* aw2 = (const float*)d_in[13];
    const float* aq2 = (const float*)d_in[14];
    const float* owp = (const float*)d_in[15];
    const float* obp = (const float*)d_in[16];
    float* out = (float*)d_out;

    char* ws = (char*)d_ws;
    size_t off = 0;
    auto alloc = [&](size_t nbytes) -> void* {
        void* p = ws + off;
        off += (nbytes + 255) & ~(size_t)255;
        return p;
    };
    // ---- zero-initialized region (contiguous from ws start) ----
    int* m0    = (int*)alloc(NN * 4);
    int* m1    = (int*)alloc(NN * 4);
    int* m2    = (int*)alloc(NN * 4);
    float* lg0 = (float*)alloc(NN * 4);
    float* lg1 = (float*)alloc(NN * 4);
    float* lg2 = (float*)alloc(NN * 4);
    int* cnts  = (int*)alloc(4 * 4);
    float* C0  = (float*)alloc((size_t)MAXL1 * 512 * 4);
    float* C1  = (float*)alloc((size_t)MAXL2 * 256 * 4);
    float* C2  = (float*)alloc(128 * 4);
    size_t zero_end = off;            // multiple of 256
    // ---- rest ----
    int* inv1  = (int*)alloc(NN * 4);
    int* inv2  = (int*)alloc(NN * 4);
    int* list0 = (int*)alloc(MAXL0 * 4);
    int* list1 = (int*)alloc(MAXL1 * 4);
    int* list2 = (int*)alloc(MAXL2 * 4);
    int* list3 = (int*)alloc(4);
    float* hN0c = (float*)alloc((size_t)MAXL1 * 1024 * 4);
    float* h1c  = (float*)alloc((size_t)MAXL1 * 512 * 4);
    float* hN1c = (float*)alloc((size_t)MAXL2 * 512 * 4);
    float* h2c  = (float*)alloc((size_t)MAXL2 * 256 * 4);
    float* hN2c = (float*)alloc(256 * 4);
    float* h3c  = (float*)alloc(128 * 4);
    (void)in_sizes; (void)n_in; (void)out_size; (void)ws_size;

    int nblk = (NN + 255) / 256;
    int nz4 = (int)(zero_end / 16);

    hipLaunchKernelGGL(k_zero, dim3((nz4 + 255) / 256), dim3(256), 0, stream, (float4*)ws, nz4);
    hipLaunchKernelGGL(k_seed, dim3(1), dim3(64), 0, stream, senders, m2, list3, cnts);
    hipLaunchKernelGGL(k_expand, dim3(nblk), dim3(256), 0, stream, senders, m2, m1, 1);
    hipLaunchKernelGGL(k_expand, dim3(nblk), dim3(256), 0, stream, senders, m1, m0, 0);
    hipLaunchKernelGGL(k_compact, dim3(nblk), dim3(256), 0, stream, m2, list2, inv2, cnts + 2);
    hipLaunchKernelGGL(k_compact, dim3(nblk), dim3(256), 0, stream, m1, list1, inv1, cnts + 1);
    hipLaunchKernelGGL(k_compact, dim3(nblk), dim3(256), 0, stream, m0, list0, (int*)nullptr, cnts + 0);

    // ---- layer 0 (din=1024, dh=512) ----
    // logits: lg0[n] = sum_c relu(X[n]@aw0)[c]*aq0[c] over list0 rows
    hipLaunchKernelGGL(k_matmul, dim3((MAXL0 + 63) / 64, 512 / 64, 1), dim3(256), 0, stream,
                       X, X, list0, (int*)nullptr, aw0, aq0, lg0, cnts + 0,
                       1, 1, 1024, 0, 512, 1024);
    hipLaunchKernelGGL(k_agg, dim3(MAXL1), dim3(256), 0, stream,
                       X, (const int*)nullptr, lg0, senders, list1, cnts + 1, hN0c, 1024);
    // h1 = relu(concat(X[list1], hN0) @ lw0 + lb0): split-K 8
    hipLaunchKernelGGL(k_matmul, dim3((MAXL1 + 63) / 64, 512 / 64, 8), dim3(256), 0, stream,
                       X, hN0c, list1, (int*)nullptr, lw0, aq0, C0, cnts + 1,
                       1, 0, 1024, 1024, 512, 256);
    hipLaunchKernelGGL(k_bias_relu, dim3((MAXL1 * 512 + 255) / 256), dim3(256), 0, stream,
                       C0, lb0, h1c, cnts + 1, 9);

    // ---- layer 1 (din=512, dh=256) ----
    hipLaunchKernelGGL(k_matmul, dim3((MAXL1 + 63) / 64, 256 / 64, 1), dim3(256), 0, stream,
                       h1c, h1c, list1, (int*)nullptr, aw1, aq1, lg1, cnts + 1,
                       0, 1, 512, 0, 256, 512);
    hipLaunchKernelGGL(k_agg, dim3(MAXL2), dim3(256), 0, stream,
                       h1c, inv1, lg1, senders, list2, cnts + 2, hN1c, 512);
    hipLaunchKernelGGL(k_matmul, dim3(1, 256 / 64, 8), dim3(256), 0, stream,
                       h1c, hN1c, list2, inv1, lw1, aq1, C1, cnts + 2,
                       2, 0, 512, 512, 256, 128);
    hipLaunchKernelGGL(k_bias_relu, dim3((MAXL2 * 256 + 255) / 256), dim3(256), 0, stream,
                       C1, lb1, h2c, cnts + 2, 8);

    // ---- layer 2 (din=256, dh=128) ----
    hipLaunchKernelGGL(k_matmul, dim3(1, 128 / 64, 1), dim3(256), 0, stream,
                       h2c, h2c, list2, (int*)nullptr, aw2, aq2, lg2, cnts + 2,
                       0, 1, 256, 0, 128, 256);
    hipLaunchKernelGGL(k_agg, dim3(1), dim3(256), 0, stream,
                       h2c, inv2, lg2, senders, list3, cnts + 3, hN2c, 256);
    hipLaunchKernelGGL(k_matmul, dim3(1, 128 / 64, 4), dim3(256), 0, stream,
                       h2c, hN2c, list3, inv2, lw2, aq2, C2, cnts + 3,
                       2, 0, 256, 256, 128, 128);
    hipLaunchKernelGGL(k_bias_relu, dim3(1), dim3(256), 0, stream,
                       C2, lb2, h3c, cnts + 3, 7);

    // ---- output ----
    hipLaunchKernelGGL(k_out, dim3(1), dim3(128), 0, stream, h3c, owp, obp, out);
}

// Round 3
// 312.933 us; speedup vs baseline: 3.0868x; 1.1052x over previous
//
#include <hip/hip_runtime.h>
#include <math.h>

typedef unsigned short ushort_t;
typedef __attribute__((ext_vector_type(8))) short short8;
typedef __attribute__((ext_vector_type(4))) float f32x4;

// Problem constants (fixed by setup_inputs)
#define NN    20000
#define DEG   16
constexpr int MAXL2 = 1 + DEG;            // 17
constexpr int MAXL1 = MAXL2 + MAXL2*DEG;  // 289
constexpr int MAXL0 = MAXL1*DEG;          // 4624
constexpr int L0PAD = 73 * 64;            // 4672 (guard-free MFMA tiles)

__device__ __forceinline__ ushort_t f2bf(float f) {
    unsigned u = __float_as_uint(f);
    return (ushort_t)((u + 0x7FFFu + ((u >> 16) & 1u)) >> 16);   // RTN-even
}

// ---------------- zero ----------------
__global__ void k_zero(float4* p, int n4) {
    int i = blockIdx.x * 256 + threadIdx.x;
    if (i < n4) p[i] = make_float4(0.f, 0.f, 0.f, 0.f);
}

// ---------------- frontier: one block, LDS-bitmap dedupe ----------------
__global__ __launch_bounds__(256)
void k_frontier(const int* __restrict__ senders,
                int* list2, int* inv2, int* list1, int* inv1,
                int* list0, int* inv0, int* cnts) {
    __shared__ unsigned bm[625];
    __shared__ int cnt;
    int t = threadIdx.x;
    auto clear = [&]() { for (int i = t; i < 625; i += 256) bm[i] = 0u; if (t == 0) cnt = 0; };
    auto tryadd = [&](int node, int* list, int* inv) {
        unsigned bit = 1u << (node & 31);
        unsigned old = atomicOr(&bm[node >> 5], bit);
        if (!(old & bit)) { int p = atomicAdd(&cnt, 1); list[p] = node; inv[node] = p; }
    };
    clear(); __syncthreads();
    if (t < 17) { int node = (t < 16) ? senders[14 * DEG + t] : 14; tryadd(node, list2, inv2); }
    __syncthreads();
    int c2 = cnt; if (t == 0) cnts[2] = c2;
    __syncthreads(); clear(); __syncthreads();
    for (int i = t; i < c2 * 17; i += 256) {
        int r = i / 17, k = i - 17 * r;
        int node = (k < 16) ? senders[list2[r] * DEG + k] : list2[r];
        tryadd(node, list1, inv1);
    }
    __syncthreads();
    int c1 = cnt; if (t == 0) cnts[1] = c1;
    __syncthreads(); clear(); __syncthreads();
    for (int i = t; i < c1 * 16; i += 256) {
        int r = i >> 4, k = i & 15;
        tryadd(senders[list1[r] * DEG + k], list0, inv0);
    }
    __syncthreads();
    if (t == 0) cnts[0] = cnt;
}

// ---------------- gather + convert X[list0] rows -> bf16, zero-pad to L0PAD ----------------
__global__ void k_cvtX(const float* __restrict__ X, const int* __restrict__ list0,
                       const int* __restrict__ cnt0, ushort_t* __restrict__ Xg) {
    int r = blockIdx.x, t = threadIdx.x;
    int rc = *cnt0;
    ushort_t o0 = 0, o1 = 0, o2 = 0, o3 = 0;
    if (r < rc) {
        float4 v = *(const float4*)(X + (size_t)list0[r] * 1024 + t * 4);
        o0 = f2bf(v.x); o1 = f2bf(v.y); o2 = f2bf(v.z); o3 = f2bf(v.w);
    }
    ushort_t* p = Xg + (size_t)r * 1024 + t * 4;
    p[0] = o0; p[1] = o1; p[2] = o2; p[3] = o3;
}

// ---------------- transpose + convert W [K][N] fp32 -> WT [N][K] bf16 ----------------
__global__ void k_cvtW(const float* __restrict__ W, ushort_t* __restrict__ WT, int K, int N) {
    __shared__ float tile[32][33];
    int t = threadIdx.x;
    int i0 = t >> 3, j0 = (t & 7) * 4;
    int k = blockIdx.y * 32 + i0, n0 = blockIdx.x * 32;
    float4 v = *(const float4*)(W + (size_t)k * N + n0 + j0);
    tile[i0][j0] = v.x; tile[i0][j0 + 1] = v.y; tile[i0][j0 + 2] = v.z; tile[i0][j0 + 3] = v.w;
    __syncthreads();
    int n = n0 + i0, kc = j0;
    ushort_t* p = WT + (size_t)n * K + blockIdx.y * 32 + kc;
    p[0] = f2bf(tile[kc][i0]); p[1] = f2bf(tile[kc + 1][i0]);
    p[2] = f2bf(tile[kc + 2][i0]); p[3] = f2bf(tile[kc + 3][i0]);
}

// ---------------- bf16 MFMA logits GEMM: lgc[r] += sum_c relu(Xg[r]@W)[c]*aq[c] ----------------
// 64x64 tile, 16x16x32 MFMA, K-step 32, register-prefetch pipeline, split-K via z.
__global__ __launch_bounds__(256)
void k_logits_mfma(const ushort_t* __restrict__ Xg,  // [L0PAD][K]
                   const ushort_t* __restrict__ WT,  // [NC][K]
                   const float* __restrict__ aq, float* __restrict__ lgc,
                   const int* __restrict__ cnt, int K, int KS) {
    __shared__ short As[64 * 40];   // row-major [64][40-pad], bf16 bits
    __shared__ short Bs[64 * 40];   // BsT: [n][k]
    int rcnt = *cnt;
    int row0 = blockIdx.x * 64;
    if (row0 >= rcnt) return;
    int col0 = blockIdx.y * 64;
    int kbeg = blockIdx.z * KS, kend = kbeg + KS;
    int t = threadIdx.x;
    int w = t >> 6, lane = t & 63;

    int sr = t >> 2, sk = (t & 3) * 8;   // staging: row 0..63, k-offset 0/8/16/24
    const ushort_t* ap = Xg + (size_t)(row0 + sr) * K + sk;
    const ushort_t* bp = WT + (size_t)(col0 + sr) * K + sk;

    int fm = lane & 15, fq = lane >> 4;
    const short* arow = As + (w * 16 + fm) * 40 + fq * 8;
    const short* brow = Bs + fm * 40 + fq * 8;

    f32x4 acc0 = {0.f,0.f,0.f,0.f}, acc1 = {0.f,0.f,0.f,0.f};
    f32x4 acc2 = {0.f,0.f,0.f,0.f}, acc3 = {0.f,0.f,0.f,0.f};

    short8 pa = *(const short8*)(ap + kbeg);
    short8 pb = *(const short8*)(bp + kbeg);
    for (int k0 = kbeg; k0 < kend; k0 += 32) {
        *(short8*)(As + sr * 40 + sk) = pa;
        *(short8*)(Bs + sr * 40 + sk) = pb;
        __syncthreads();
        if (k0 + 32 < kend) {
            pa = *(const short8*)(ap + k0 + 32);
            pb = *(const short8*)(bp + k0 + 32);
        }
        short8 af = *(const short8*)arow;
        short8 b0 = *(const short8*)(brow);
        short8 b1 = *(const short8*)(brow + 16 * 40);
        short8 b2 = *(const short8*)(brow + 32 * 40);
        short8 b3 = *(const short8*)(brow + 48 * 40);
        acc0 = __builtin_amdgcn_mfma_f32_16x16x32_bf16(af, b0, acc0, 0, 0, 0);
        acc1 = __builtin_amdgcn_mfma_f32_16x16x32_bf16(af, b1, acc1, 0, 0, 0);
        acc2 = __builtin_amdgcn_mfma_f32_16x16x32_bf16(af, b2, acc2, 0, 0, 0);
        acc3 = __builtin_amdgcn_mfma_f32_16x16x32_bf16(af, b3, acc3, 0, 0, 0);
        __syncthreads();
    }

    // epilogue: rowsum of relu(D)*aq; D layout: row = fq*4+r (+w*16), col = fm (+16j)
    float aqv0 = aq[col0 + fm], aqv1 = aq[col0 + 16 + fm];
    float aqv2 = aq[col0 + 32 + fm], aqv3 = aq[col0 + 48 + fm];
#pragma unroll
    for (int r = 0; r < 4; r++) {
        float v = fmaxf(acc0[r], 0.f) * aqv0 + fmaxf(acc1[r], 0.f) * aqv1
                + fmaxf(acc2[r], 0.f) * aqv2 + fmaxf(acc3[r], 0.f) * aqv3;
#pragma unroll
        for (int off = 1; off < 16; off <<= 1) v += __shfl_xor(v, off);
        if (fm == 0) atomicAdd(&lgc[row0 + w * 16 + fq * 4 + r], v);
    }
}

// ---------------- generic pipelined fp32 GEMM (64x64, BK=32) ----------------
// omode 0: C[r*NC+c] += acc (atomic, split-K);  omode 1: lgc[r] += sum_c relu(acc)*aq[c]
__global__ __launch_bounds__(256)
void k_matmul(const float* __restrict__ A1, const float* __restrict__ A2,
              const int* __restrict__ list, const int* __restrict__ inv,
              const float* __restrict__ B, const float* __restrict__ aq,
              float* __restrict__ C, const int* __restrict__ cnt,
              int amode, int omode, int K1, int K2, int NC, int KS) {
    __shared__ float As[32][68];
    __shared__ float Bs[32][64];
    __shared__ float rowsum[64];

    int rcnt = *cnt;
    int row0 = blockIdx.x * 64;
    if (row0 >= rcnt) return;
    int col0 = blockIdx.y * 64;
    int K = K1 + K2;
    int kbeg = blockIdx.z * KS;
    int kend = kbeg + KS; if (kend > K) kend = K;

    int t = threadIdx.x;
    int ty = t >> 4, tx = t & 15;
    int lr = t >> 2, kaoff = (t & 3) * 4;
    int grow = row0 + lr;
    bool rowValid = grow < rcnt;
    const float* rp1 = A1;
    const float* rp2 = A2;
    if (rowValid) {
        int hrow;
        if (amode == 0) hrow = grow;
        else { int node = list[grow]; hrow = (amode == 2) ? inv[node] : node; }
        rp1 = A1 + (size_t)hrow * K1;
        rp2 = A2 + (size_t)grow * K2;
    }
    const float* Bp = B + col0;
    int bidx0 = t, bidx1 = t + 256;

    auto loadA = [&](int k) -> float4 {
        if (!rowValid) return make_float4(0.f, 0.f, 0.f, 0.f);
        const float* src = (k < K1) ? (rp1 + k) : (rp2 + (k - K1));
        return *(const float4*)src;
    };
    auto loadB = [&](int idx, int k0) -> float4 {
        int row = idx >> 4, c4 = (idx & 15) * 4;
        return *(const float4*)(Bp + (size_t)(k0 + row) * NC + c4);
    };

    float4 pa0 = loadA(kbeg + kaoff);
    float4 pa1 = loadA(kbeg + kaoff + 16);
    float4 pb0 = loadB(bidx0, kbeg);
    float4 pb1 = loadB(bidx1, kbeg);

    float acc[4][4] = {};
    for (int k0 = kbeg; k0 < kend; k0 += 32) {
        As[kaoff + 0][lr] = pa0.x; As[kaoff + 1][lr] = pa0.y;
        As[kaoff + 2][lr] = pa0.z; As[kaoff + 3][lr] = pa0.w;
        As[kaoff + 16][lr] = pa1.x; As[kaoff + 17][lr] = pa1.y;
        As[kaoff + 18][lr] = pa1.z; As[kaoff + 19][lr] = pa1.w;
        *(float4*)&Bs[bidx0 >> 4][(bidx0 & 15) * 4] = pb0;
        *(float4*)&Bs[bidx1 >> 4][(bidx1 & 15) * 4] = pb1;
        __syncthreads();
        if (k0 + 32 < kend) {
            pa0 = loadA(k0 + 32 + kaoff);
            pa1 = loadA(k0 + 32 + kaoff + 16);
            pb0 = loadB(bidx0, k0 + 32);
            pb1 = loadB(bidx1, k0 + 32);
        }
#pragma unroll
        for (int kk = 0; kk < 32; kk++) {
            float4 a4 = *(const float4*)&As[kk][ty * 4];
            float4 b4 = *(const float4*)&Bs[kk][tx * 4];
            float a[4] = {a4.x, a4.y, a4.z, a4.w};
            float b[4] = {b4.x, b4.y, b4.z, b4.w};
#pragma unroll
            for (int i = 0; i < 4; i++)
#pragma unroll
                for (int j = 0; j < 4; j++) acc[i][j] += a[i] * b[j];
        }
        __syncthreads();
    }

    if (omode == 0) {
#pragma unroll
        for (int i = 0; i < 4; i++) {
            int r = row0 + ty * 4 + i;
            if (r < rcnt) {
                float* Crow = C + (size_t)r * NC + col0 + tx * 4;
#pragma unroll
                for (int j = 0; j < 4; j++) atomicAdd(&Crow[j], acc[i][j]);
            }
        }
    } else {
        if (t < 64) rowsum[t] = 0.f;
        __syncthreads();
        float aqv[4];
#pragma unroll
        for (int j = 0; j < 4; j++) aqv[j] = aq[col0 + tx * 4 + j];
#pragma unroll
        for (int i = 0; i < 4; i++) {
            float s = 0.f;
#pragma unroll
            for (int j = 0; j < 4; j++) {
                float v = acc[i][j];
                v = v > 0.f ? v : 0.f;
                s += v * aqv[j];
            }
            atomicAdd(&rowsum[ty * 4 + i], s);
        }
        __syncthreads();
        if (t < 64) {
            int r = row0 + t;
            if (r < rcnt) atomicAdd(&C[r], rowsum[t]);   // compact logits
        }
    }
}

// ---------------- bias + relu epilogue ----------------
__global__ void k_bias_relu(const float* __restrict__ C, const float* __restrict__ b,
                            float* __restrict__ H, const int* __restrict__ cnt, int ncShift) {
    int rcnt = *cnt;
    int NC = 1 << ncShift;
    int e = blockIdx.x * 256 + threadIdx.x;
    int r = e >> ncShift;
    if (r >= rcnt) return;
    int c = e & (NC - 1);
    float v = C[(size_t)r * NC + c] + b[c];
    H[(size_t)r * NC + c] = v > 0.f ? v : 0.f;
}

// ---------------- attention aggregate ----------------
__global__ __launch_bounds__(256)
void k_agg(const float* __restrict__ Hsrc, const int* __restrict__ invH,
           const float* __restrict__ lgc, const int* __restrict__ invL,
           const int* __restrict__ senders,
           const int* __restrict__ listN, const int* __restrict__ cntN,
           float* __restrict__ hN, int din) {
    __shared__ int   s_row[DEG];
    __shared__ float s_w[DEG];
    __shared__ float s_scale;
    int b = blockIdx.x;
    if (b >= *cntN) return;
    int n = listN[b];
    int t = threadIdx.x;
    if (t < DEG) {
        int s = senders[n * DEG + t];
        s_row[t] = invH ? invH[s] : s;
        s_w[t] = lgc[invL ? invL[s] : s];
    }
    __syncthreads();
    if (t == 0) {
        float m = -1e30f;
        for (int k = 0; k < DEG; k++) m = fmaxf(m, s_w[k]);
        float d = 0.f;
        for (int k = 0; k < DEG; k++) { float w = expf(s_w[k] - m); s_w[k] = w; d += w; }
        s_scale = 1.f / d;
    }
    __syncthreads();
    float scale = s_scale;
    for (int dI = t; dI < din; dI += 256) {
        float acc = 0.f;
#pragma unroll
        for (int k = 0; k < DEG; k++)
            acc += s_w[k] * Hsrc[(size_t)s_row[k] * din + dI];
        hN[(size_t)b * din + dI] = acc * scale;
    }
}

// ---------------- fused layer 2 + output (single block) ----------------
__global__ __launch_bounds__(256)
void k_layer2(const float* __restrict__ h2c, const int* __restrict__ inv2,
              const int* __restrict__ senders,
              const float* __restrict__ aw2, const float* __restrict__ aq2,
              const float* __restrict__ lw2, const float* __restrict__ lb2,
              const float* __restrict__ ow, const float* __restrict__ ob,
              const int* __restrict__ cnt2, float* __restrict__ out) {
    __shared__ float h2s[17][256];
    __shared__ float pl[17][128];
    __shared__ float lg[17];
    __shared__ float wgt[16];
    __shared__ int   srow[16];
    __shared__ int   iv14s;
    __shared__ float hcat[512];
    __shared__ float h3[128];
    int t = threadIdx.x;
    int rc = *cnt2;   // <= 17
    for (int i = t; i < rc * 256; i += 256) { int r = i >> 8, c = i & 255; h2s[r][c] = h2c[r * 256 + c]; }
    if (t < 17) lg[t] = 0.f;
    if (t == 0) iv14s = inv2[14];
    __syncthreads();

    // logits[r] = sum_c relu( h2s[r] . aw2[:,c] ) * aq2[c]
    int c = t & 127, h = t >> 7;   // h: k-half (wave-uniform)
    float acc[17];
#pragma unroll
    for (int i = 0; i < 17; i++) acc[i] = 0.f;
    for (int k4 = h * 32; k4 < h * 32 + 32; k4++) {
        int k = k4 * 4;
        float w0 = aw2[(size_t)k * 128 + c];
        float w1 = aw2[(size_t)(k + 1) * 128 + c];
        float w2 = aw2[(size_t)(k + 2) * 128 + c];
        float w3 = aw2[(size_t)(k + 3) * 128 + c];
        for (int r = 0; r < rc; r++) {
            float4 hv = *(const float4*)&h2s[r][k4 * 4];
            acc[r] += hv.x * w0 + hv.y * w1 + hv.z * w2 + hv.w * w3;
        }
    }
    if (h == 1) { for (int r = 0; r < rc; r++) pl[r][c] = acc[r]; }
    __syncthreads();
    if (h == 0) {
        float aqv = aq2[c];
        for (int r = 0; r < rc; r++) {
            float v = acc[r] + pl[r][c];
            v = (v > 0.f ? v : 0.f) * aqv;
#pragma unroll
            for (int off = 1; off < 64; off <<= 1) v += __shfl_xor(v, off);
            if ((t & 63) == 0) atomicAdd(&lg[r], v);
        }
    }
    __syncthreads();
    if (t == 0) {
        float m = -1e30f; float l[16];
        for (int k = 0; k < 16; k++) {
            int s = senders[14 * DEG + k];
            int r = inv2[s];
            srow[k] = r; l[k] = lg[r];
            m = fmaxf(m, l[k]);
        }
        float d = 0.f;
        for (int k = 0; k < 16; k++) { float w = expf(l[k] - m); wgt[k] = w; d += w; }
        float invd = 1.f / d;
        for (int k = 0; k < 16; k++) wgt[k] *= invd;
    }
    __syncthreads();
    {   // hN2 + concat
        float a = 0.f;
        int cc = t & 255;
        if (t < 256) {
#pragma unroll
            for (int k = 0; k < 16; k++) a += wgt[k] * h2s[srow[k]][cc];
            hcat[256 + cc] = a;
            hcat[cc] = h2s[iv14s][cc];
        }
    }
    __syncthreads();
    if (t < 128) {
        float a = lb2[t];
        for (int k = 0; k < 512; k++) a += hcat[k] * lw2[(size_t)k * 128 + t];
        h3[t] = a > 0.f ? a : 0.f;
    }
    __syncthreads();
    if (t < 128) {
        float a = ob[t];
        for (int k = 0; k < 128; k++) a += h3[k] * ow[(size_t)k * 128 + t];
        out[t] = a;
    }
}

// ---------------- launch ----------------
extern "C" void kernel_launch(void* const* d_in, const int* in_sizes, int n_in,
                              void* d_out, int out_size, void* d_ws, size_t ws_size,
                              hipStream_t stream) {
    const float* X       = (const float*)d_in[0];
    const int*   senders = (const int*)d_in[1];
    const float* lw0 = (const float*)d_in[3];
    const float* lb0 = (const float*)d_in[4];
    const float* aw0 = (const float*)d_in[5];
    const float* aq0 = (const float*)d_in[6];
    const float* lw1 = (const float*)d_in[7];
    const float* lb1 = (const float*)d_in[8];
    const float* aw1 = (const float*)d_in[9];
    const float* aq1 = (const float*)d_in[10];
    const float* lw2 = (const float*)d_in[11];
    const float* lb2 = (const float*)d_in[12];
    const float* aw2 = (const float*)d_in[13];
    const float* aq2 = (const float*)d_in[14];
    const float* owp = (const float*)d_in[15];
    const float* obp = (const float*)d_in[16];
    float* out = (float*)d_out;

    char* ws = (char*)d_ws;
    size_t off = 0;
    auto alloc = [&](size_t nbytes) -> void* {
        void* p = ws + off;
        off += (nbytes + 255) & ~(size_t)255;
        return p;
    };
    // ---- zero-initialized region (contiguous from ws start) ----
    float* lgc0 = (float*)alloc(L0PAD * 4);
    float* lgc1 = (float*)alloc(MAXL1 * 4);
    float* C0   = (float*)alloc((size_t)MAXL1 * 512 * 4);
    float* C1   = (float*)alloc((size_t)MAXL2 * 256 * 4);
    size_t zero_end = off;
    // ---- rest ----
    int* inv0  = (int*)alloc(NN * 4);
    int* inv1  = (int*)alloc(NN * 4);
    int* inv2  = (int*)alloc(NN * 4);
    int* list0 = (int*)alloc(L0PAD * 4);
    int* list1 = (int*)alloc(MAXL1 * 4);
    int* list2 = (int*)alloc(MAXL2 * 4);
    int* cnts  = (int*)alloc(4 * 4);
    ushort_t* Xg  = (ushort_t*)alloc((size_t)L0PAD * 1024 * 2);  // bf16
    ushort_t* awT = (ushort_t*)alloc((size_t)512 * 1024 * 2);    // bf16 [N][K]
    float* hN0c = (float*)alloc((size_t)MAXL1 * 1024 * 4);
    float* h1c  = (float*)alloc((size_t)MAXL1 * 512 * 4);
    float* hN1c = (float*)alloc((size_t)MAXL2 * 512 * 4);
    float* h2c  = (float*)alloc((size_t)MAXL2 * 256 * 4);
    (void)in_sizes; (void)n_in; (void)out_size; (void)ws_size;

    int nz4 = (int)(zero_end / 16);
    hipLaunchKernelGGL(k_zero, dim3((nz4 + 255) / 256), dim3(256), 0, stream, (float4*)ws, nz4);
    hipLaunchKernelGGL(k_frontier, dim3(1), dim3(256), 0, stream,
                       senders, list2, inv2, list1, inv1, list0, inv0, cnts);
    hipLaunchKernelGGL(k_cvtW, dim3(512 / 32, 1024 / 32), dim3(256), 0, stream, aw0, awT, 1024, 512);
    hipLaunchKernelGGL(k_cvtX, dim3(L0PAD), dim3(256), 0, stream, X, list0, cnts + 0, Xg);

    // ---- layer 0 (din=1024, dh=512) ----
    hipLaunchKernelGGL(k_logits_mfma, dim3(73, 512 / 64, 2), dim3(256), 0, stream,
                       Xg, awT, aq0, lgc0, cnts + 0, 1024, 512);
    hipLaunchKernelGGL(k_agg, dim3(MAXL1), dim3(256), 0, stream,
                       X, (const int*)nullptr, lgc0, inv0, senders, list1, cnts + 1, hN0c, 1024);
    hipLaunchKernelGGL(k_matmul, dim3((MAXL1 + 63) / 64, 512 / 64, 8), dim3(256), 0, stream,
                       X, hN0c, list1, (int*)nullptr, lw0, aq0, C0, cnts + 1,
                       1, 0, 1024, 1024, 512, 256);
    hipLaunchKernelGGL(k_bias_relu, dim3((MAXL1 * 512 + 255) / 256), dim3(256), 0, stream,
                       C0, lb0, h1c, cnts + 1, 9);

    // ---- layer 1 (din=512, dh=256) ----
    hipLaunchKernelGGL(k_matmul, dim3((MAXL1 + 63) / 64, 256 / 64, 2), dim3(256), 0, stream,
                       h1c, h1c, list1, (int*)nullptr, aw1, aq1, lgc1, cnts + 1,
                       0, 1, 512, 0, 256, 256);
    hipLaunchKernelGGL(k_agg, dim3(MAXL2), dim3(256), 0, stream,
                       h1c, inv1, lgc1, inv1, senders, list2, cnts + 2, hN1c, 512);
    hipLaunchKernelGGL(k_matmul, dim3(1, 256 / 64, 8), dim3(256), 0, stream,
                       h1c, hN1c, list2, inv1, lw1, aq1, C1, cnts + 2,
                       2, 0, 512, 512, 256, 128);
    hipLaunchKernelGGL(k_bias_relu, dim3((MAXL2 * 256 + 255) / 256), dim3(256), 0, stream,
                       C1, lb1, h2c, cnts + 2, 8);

    // ---- layer 2 + output (fused, single block) ----
    hipLaunchKernelGGL(k_layer2, dim3(1), dim3(256), 0, stream,
                       h2c, inv2, senders, aw2, aq2, lw2, lb2, owp, obp, cnts + 2, out);
}

// Round 4
// 292.415 us; speedup vs baseline: 3.3034x; 1.0702x over previous
//
#include <hip/hip_runtime.h>
#include <math.h>

typedef unsigned short ushort_t;
typedef __attribute__((ext_vector_type(8))) short short8;
typedef __attribute__((ext_vector_type(4))) float f32x4;

// Problem constants (fixed by setup_inputs)
#define NN    20000
#define DEG   16
constexpr int MAXL2 = 1 + DEG;            // 17
constexpr int MAXL1 = MAXL2 + MAXL2*DEG;  // 289
constexpr int MAXL0 = MAXL1*DEG;          // 4624
constexpr int L0PAD = 73 * 64;            // 4672 (guard-free MFMA tiles)
constexpr int NWBLK = 512;                // cvtW tile-blocks (16 x 32)

__device__ __forceinline__ ushort_t f2bf(float f) {
    unsigned u = __float_as_uint(f);
    return (ushort_t)((u + 0x7FFFu + ((u >> 16) & 1u)) >> 16);   // RTN-even
}

// ---------------- frontier (block 0) + workspace zero (blocks 1..) ----------------
__global__ __launch_bounds__(256)
void k_frontier(const int* __restrict__ senders,
                int* list2, int* inv2, int* list1, int* inv1,
                int* list0, int* inv0, int* cnts, float4* zp, int n4) {
    int t = threadIdx.x;
    if (blockIdx.x > 0) {
        int i = (blockIdx.x - 1) * 256 + t;
        if (i < n4) zp[i] = make_float4(0.f, 0.f, 0.f, 0.f);
        return;
    }
    __shared__ unsigned bm[625];
    __shared__ int cnt;
    auto clear = [&]() { for (int i = t; i < 625; i += 256) bm[i] = 0u; if (t == 0) cnt = 0; };
    auto tryadd = [&](int node, int* list, int* inv) {
        unsigned bit = 1u << (node & 31);
        unsigned old = atomicOr(&bm[node >> 5], bit);
        if (!(old & bit)) { int p = atomicAdd(&cnt, 1); list[p] = node; inv[node] = p; }
    };
    clear(); __syncthreads();
    if (t < 17) { int node = (t < 16) ? senders[14 * DEG + t] : 14; tryadd(node, list2, inv2); }
    __syncthreads();
    int c2 = cnt; if (t == 0) cnts[2] = c2;
    __syncthreads(); clear(); __syncthreads();
    for (int i = t; i < c2 * 17; i += 256) {
        int r = i / 17, k = i - 17 * r;
        int node = (k < 16) ? senders[list2[r] * DEG + k] : list2[r];
        tryadd(node, list1, inv1);
    }
    __syncthreads();
    int c1 = cnt; if (t == 0) cnts[1] = c1;
    __syncthreads(); clear(); __syncthreads();
    for (int i = t; i < c1 * 16; i += 256) {
        int r = i >> 4, k = i & 15;
        tryadd(senders[list1[r] * DEG + k], list0, inv0);
    }
    __syncthreads();
    if (t == 0) cnts[0] = cnt;
}

// ---------------- fused prep: transpose aw0 -> bf16 [N][K]  +  gather X[list0] -> bf16 ----------------
__global__ __launch_bounds__(256)
void k_prep(const float* __restrict__ W, ushort_t* __restrict__ WT,
            const float* __restrict__ X, const int* __restrict__ list0,
            const int* __restrict__ cnt0, ushort_t* __restrict__ Xg) {
    int t = threadIdx.x;
    if (blockIdx.x < NWBLK) {
        // aw0 [K=1024][N=512] -> WT [512][1024]
        __shared__ float tile[32][33];
        int b = blockIdx.x;
        int bx = b & 15, by = b >> 4;
        int i0 = t >> 3, j0 = (t & 7) * 4;
        int k = by * 32 + i0, n0 = bx * 32;
        float4 v = *(const float4*)(W + (size_t)k * 512 + n0 + j0);
        tile[i0][j0] = v.x; tile[i0][j0 + 1] = v.y; tile[i0][j0 + 2] = v.z; tile[i0][j0 + 3] = v.w;
        __syncthreads();
        int n = n0 + i0, kc = j0;
        ushort_t* p = WT + (size_t)n * 1024 + by * 32 + kc;
        p[0] = f2bf(tile[kc][i0]); p[1] = f2bf(tile[kc + 1][i0]);
        p[2] = f2bf(tile[kc + 2][i0]); p[3] = f2bf(tile[kc + 3][i0]);
    } else {
        int r = blockIdx.x - NWBLK;
        int rc = *cnt0;
        ushort_t o0 = 0, o1 = 0, o2 = 0, o3 = 0;
        if (r < rc) {
            float4 v = *(const float4*)(X + (size_t)list0[r] * 1024 + t * 4);
            o0 = f2bf(v.x); o1 = f2bf(v.y); o2 = f2bf(v.z); o3 = f2bf(v.w);
        }
        ushort_t* p = Xg + (size_t)r * 1024 + t * 4;
        p[0] = o0; p[1] = o1; p[2] = o2; p[3] = o3;
    }
}

// ---------------- bf16 MFMA logits GEMM: lgc[r] += sum_c relu(Xg[r]@W)[c]*aq[c] ----------------
__global__ __launch_bounds__(256)
void k_logits_mfma(const ushort_t* __restrict__ Xg,  // [L0PAD][K]
                   const ushort_t* __restrict__ WT,  // [NC][K]
                   const float* __restrict__ aq, float* __restrict__ lgc,
                   const int* __restrict__ cnt, int K, int KS) {
    __shared__ short As[64 * 40];
    __shared__ short Bs[64 * 40];
    int rcnt = *cnt;
    int row0 = blockIdx.x * 64;
    if (row0 >= rcnt) return;
    int col0 = blockIdx.y * 64;
    int kbeg = blockIdx.z * KS, kend = kbeg + KS;
    int t = threadIdx.x;
    int w = t >> 6, lane = t & 63;

    int sr = t >> 2, sk = (t & 3) * 8;
    const ushort_t* ap = Xg + (size_t)(row0 + sr) * K + sk;
    const ushort_t* bp = WT + (size_t)(col0 + sr) * K + sk;

    int fm = lane & 15, fq = lane >> 4;
    const short* arow = As + (w * 16 + fm) * 40 + fq * 8;
    const short* brow = Bs + fm * 40 + fq * 8;

    f32x4 acc0 = {0.f,0.f,0.f,0.f}, acc1 = {0.f,0.f,0.f,0.f};
    f32x4 acc2 = {0.f,0.f,0.f,0.f}, acc3 = {0.f,0.f,0.f,0.f};

    short8 pa = *(const short8*)(ap + kbeg);
    short8 pb = *(const short8*)(bp + kbeg);
    for (int k0 = kbeg; k0 < kend; k0 += 32) {
        *(short8*)(As + sr * 40 + sk) = pa;
        *(short8*)(Bs + sr * 40 + sk) = pb;
        __syncthreads();
        if (k0 + 32 < kend) {
            pa = *(const short8*)(ap + k0 + 32);
            pb = *(const short8*)(bp + k0 + 32);
        }
        short8 af = *(const short8*)arow;
        short8 b0 = *(const short8*)(brow);
        short8 b1 = *(const short8*)(brow + 16 * 40);
        short8 b2 = *(const short8*)(brow + 32 * 40);
        short8 b3 = *(const short8*)(brow + 48 * 40);
        acc0 = __builtin_amdgcn_mfma_f32_16x16x32_bf16(af, b0, acc0, 0, 0, 0);
        acc1 = __builtin_amdgcn_mfma_f32_16x16x32_bf16(af, b1, acc1, 0, 0, 0);
        acc2 = __builtin_amdgcn_mfma_f32_16x16x32_bf16(af, b2, acc2, 0, 0, 0);
        acc3 = __builtin_amdgcn_mfma_f32_16x16x32_bf16(af, b3, acc3, 0, 0, 0);
        __syncthreads();
    }

    float aqv0 = aq[col0 + fm], aqv1 = aq[col0 + 16 + fm];
    float aqv2 = aq[col0 + 32 + fm], aqv3 = aq[col0 + 48 + fm];
#pragma unroll
    for (int r = 0; r < 4; r++) {
        float v = fmaxf(acc0[r], 0.f) * aqv0 + fmaxf(acc1[r], 0.f) * aqv1
                + fmaxf(acc2[r], 0.f) * aqv2 + fmaxf(acc3[r], 0.f) * aqv3;
#pragma unroll
        for (int off = 1; off < 16; off <<= 1) v += __shfl_xor(v, off);
        if (fm == 0) atomicAdd(&lgc[row0 + w * 16 + fq * 4 + r], v);
    }
}

// ---------------- generic pipelined fp32 GEMM (64x64, BK=32) ----------------
__global__ __launch_bounds__(256)
void k_matmul(const float* __restrict__ A1, const float* __restrict__ A2,
              const int* __restrict__ list, const int* __restrict__ inv,
              const float* __restrict__ B, const float* __restrict__ aq,
              float* __restrict__ C, const int* __restrict__ cnt,
              int amode, int omode, int K1, int K2, int NC, int KS) {
    __shared__ float As[32][68];
    __shared__ float Bs[32][64];
    __shared__ float rowsum[64];

    int rcnt = *cnt;
    int row0 = blockIdx.x * 64;
    if (row0 >= rcnt) return;
    int col0 = blockIdx.y * 64;
    int K = K1 + K2;
    int kbeg = blockIdx.z * KS;
    int kend = kbeg + KS; if (kend > K) kend = K;

    int t = threadIdx.x;
    int ty = t >> 4, tx = t & 15;
    int lr = t >> 2, kaoff = (t & 3) * 4;
    int grow = row0 + lr;
    bool rowValid = grow < rcnt;
    const float* rp1 = A1;
    const float* rp2 = A2;
    if (rowValid) {
        int hrow;
        if (amode == 0) hrow = grow;
        else { int node = list[grow]; hrow = (amode == 2) ? inv[node] : node; }
        rp1 = A1 + (size_t)hrow * K1;
        rp2 = A2 + (size_t)grow * K2;
    }
    const float* Bp = B + col0;
    int bidx0 = t, bidx1 = t + 256;

    auto loadA = [&](int k) -> float4 {
        if (!rowValid) return make_float4(0.f, 0.f, 0.f, 0.f);
        const float* src = (k < K1) ? (rp1 + k) : (rp2 + (k - K1));
        return *(const float4*)src;
    };
    auto loadB = [&](int idx, int k0) -> float4 {
        int row = idx >> 4, c4 = (idx & 15) * 4;
        return *(const float4*)(Bp + (size_t)(k0 + row) * NC + c4);
    };

    float4 pa0 = loadA(kbeg + kaoff);
    float4 pa1 = loadA(kbeg + kaoff + 16);
    float4 pb0 = loadB(bidx0, kbeg);
    float4 pb1 = loadB(bidx1, kbeg);

    float acc[4][4] = {};
    for (int k0 = kbeg; k0 < kend; k0 += 32) {
        As[kaoff + 0][lr] = pa0.x; As[kaoff + 1][lr] = pa0.y;
        As[kaoff + 2][lr] = pa0.z; As[kaoff + 3][lr] = pa0.w;
        As[kaoff + 16][lr] = pa1.x; As[kaoff + 17][lr] = pa1.y;
        As[kaoff + 18][lr] = pa1.z; As[kaoff + 19][lr] = pa1.w;
        *(float4*)&Bs[bidx0 >> 4][(bidx0 & 15) * 4] = pb0;
        *(float4*)&Bs[bidx1 >> 4][(bidx1 & 15) * 4] = pb1;
        __syncthreads();
        if (k0 + 32 < kend) {
            pa0 = loadA(k0 + 32 + kaoff);
            pa1 = loadA(k0 + 32 + kaoff + 16);
            pb0 = loadB(bidx0, k0 + 32);
            pb1 = loadB(bidx1, k0 + 32);
        }
#pragma unroll
        for (int kk = 0; kk < 32; kk++) {
            float4 a4 = *(const float4*)&As[kk][ty * 4];
            float4 b4 = *(const float4*)&Bs[kk][tx * 4];
            float a[4] = {a4.x, a4.y, a4.z, a4.w};
            float b[4] = {b4.x, b4.y, b4.z, b4.w};
#pragma unroll
            for (int i = 0; i < 4; i++)
#pragma unroll
                for (int j = 0; j < 4; j++) acc[i][j] += a[i] * b[j];
        }
        __syncthreads();
    }

    if (omode == 0) {
#pragma unroll
        for (int i = 0; i < 4; i++) {
            int r = row0 + ty * 4 + i;
            if (r < rcnt) {
                float* Crow = C + (size_t)r * NC + col0 + tx * 4;
#pragma unroll
                for (int j = 0; j < 4; j++) atomicAdd(&Crow[j], acc[i][j]);
            }
        }
    } else {
        if (t < 64) rowsum[t] = 0.f;
        __syncthreads();
        float aqv[4];
#pragma unroll
        for (int j = 0; j < 4; j++) aqv[j] = aq[col0 + tx * 4 + j];
#pragma unroll
        for (int i = 0; i < 4; i++) {
            float s = 0.f;
#pragma unroll
            for (int j = 0; j < 4; j++) {
                float v = acc[i][j];
                v = v > 0.f ? v : 0.f;
                s += v * aqv[j];
            }
            atomicAdd(&rowsum[ty * 4 + i], s);
        }
        __syncthreads();
        if (t < 64) {
            int r = row0 + t;
            if (r < rcnt) atomicAdd(&C[r], rowsum[t]);
        }
    }
}

// ---------------- bias + relu epilogue ----------------
__global__ void k_bias_relu(const float* __restrict__ C, const float* __restrict__ b,
                            float* __restrict__ H, const int* __restrict__ cnt, int ncShift) {
    int rcnt = *cnt;
    int NC = 1 << ncShift;
    int e = blockIdx.x * 256 + threadIdx.x;
    int r = e >> ncShift;
    if (r >= rcnt) return;
    int c = e & (NC - 1);
    float v = C[(size_t)r * NC + c] + b[c];
    H[(size_t)r * NC + c] = v > 0.f ? v : 0.f;
}

// ---------------- attention aggregate ----------------
__global__ __launch_bounds__(256)
void k_agg(const float* __restrict__ Hsrc, const int* __restrict__ invH,
           const float* __restrict__ lgc, const int* __restrict__ invL,
           const int* __restrict__ senders,
           const int* __restrict__ listN, const int* __restrict__ cntN,
           float* __restrict__ hN, int din) {
    __shared__ int   s_row[DEG];
    __shared__ float s_w[DEG];
    __shared__ float s_scale;
    int b = blockIdx.x;
    if (b >= *cntN) return;
    int n = listN[b];
    int t = threadIdx.x;
    if (t < DEG) {
        int s = senders[n * DEG + t];
        s_row[t] = invH ? invH[s] : s;
        s_w[t] = lgc[invL ? invL[s] : s];
    }
    __syncthreads();
    if (t == 0) {
        float m = -1e30f;
        for (int k = 0; k < DEG; k++) m = fmaxf(m, s_w[k]);
        float d = 0.f;
        for (int k = 0; k < DEG; k++) { float w = expf(s_w[k] - m); s_w[k] = w; d += w; }
        s_scale = 1.f / d;
    }
    __syncthreads();
    float scale = s_scale;
    for (int dI = t; dI < din; dI += 256) {
        float acc = 0.f;
#pragma unroll
        for (int k = 0; k < DEG; k++)
            acc += s_w[k] * Hsrc[(size_t)s_row[k] * din + dI];
        hN[(size_t)b * din + dI] = acc * scale;
    }
}

// ---------------- fused layer 2 + output (single block) ----------------
// NOTE: all acc[]-indexed loops are compile-time 17 iterations — a runtime
// bound (rc) forced acc[] into scratch (75 us, VALUBusy 0.05%). h2s rows
// >= rc are zeroed so the extra iterations compute harmless zeros.
__global__ __launch_bounds__(256)
void k_layer2(const float* __restrict__ h2c, const int* __restrict__ inv2,
              const int* __restrict__ senders,
              const float* __restrict__ aw2, const float* __restrict__ aq2,
              const float* __restrict__ lw2, const float* __restrict__ lb2,
              const float* __restrict__ ow, const float* __restrict__ ob,
              const int* __restrict__ cnt2, float* __restrict__ out) {
    __shared__ float h2s[17][256];
    __shared__ float pl[17][128];
    __shared__ float lg[17];
    __shared__ float wgt[16];
    __shared__ int   srow[16];
    __shared__ int   iv14s;
    __shared__ float hcat[512];
    __shared__ float h3[128];
    int t = threadIdx.x;
    int rc = *cnt2;   // <= 17
    for (int i = t; i < 17 * 256; i += 256) {
        int r = i >> 8, c = i & 255;
        h2s[r][c] = (r < rc) ? h2c[r * 256 + c] : 0.f;
    }
    if (t < 17) lg[t] = 0.f;
    if (t == 0) iv14s = inv2[14];
    __syncthreads();

    // logits[r] = sum_c relu( h2s[r] . aw2[:,c] ) * aq2[c]
    int c = t & 127, h = t >> 7;   // h: k-half (wave-uniform)
    float acc[17];
#pragma unroll
    for (int i = 0; i < 17; i++) acc[i] = 0.f;
    for (int k4 = h * 32; k4 < h * 32 + 32; k4++) {
        int k = k4 * 4;
        float w0 = aw2[(size_t)k * 128 + c];
        float w1 = aw2[(size_t)(k + 1) * 128 + c];
        float w2 = aw2[(size_t)(k + 2) * 128 + c];
        float w3 = aw2[(size_t)(k + 3) * 128 + c];
#pragma unroll
        for (int r = 0; r < 17; r++) {
            float4 hv = *(const float4*)&h2s[r][k4 * 4];
            acc[r] += hv.x * w0 + hv.y * w1 + hv.z * w2 + hv.w * w3;
        }
    }
    if (h == 1) {
#pragma unroll
        for (int r = 0; r < 17; r++) pl[r][c] = acc[r];
    }
    __syncthreads();
    if (h == 0) {
        float aqv = aq2[c];
#pragma unroll
        for (int r = 0; r < 17; r++) {
            float v = acc[r] + pl[r][c];
            v = (v > 0.f ? v : 0.f) * aqv;
#pragma unroll
            for (int off = 1; off < 64; off <<= 1) v += __shfl_xor(v, off);
            if ((t & 63) == 0) atomicAdd(&lg[r], v);
        }
    }
    __syncthreads();
    if (t == 0) {
        float m = -1e30f; float l[16];
#pragma unroll
        for (int k = 0; k < 16; k++) {
            int s = senders[14 * DEG + k];
            int r = inv2[s];
            srow[k] = r; l[k] = lg[r];
            m = fmaxf(m, l[k]);
        }
        float d = 0.f;
#pragma unroll
        for (int k = 0; k < 16; k++) { float w = expf(l[k] - m); wgt[k] = w; d += w; }
        float invd = 1.f / d;
#pragma unroll
        for (int k = 0; k < 16; k++) wgt[k] *= invd;
    }
    __syncthreads();
    {   // hN2 + concat
        float a = 0.f;
        int cc = t & 255;
        if (t < 256) {
#pragma unroll
            for (int k = 0; k < 16; k++) a += wgt[k] * h2s[srow[k]][cc];
            hcat[256 + cc] = a;
            hcat[cc] = h2s[iv14s][cc];
        }
    }
    __syncthreads();
    if (t < 128) {
        float a = lb2[t];
        for (int k = 0; k < 512; k++) a += hcat[k] * lw2[(size_t)k * 128 + t];
        h3[t] = a > 0.f ? a : 0.f;
    }
    __syncthreads();
    if (t < 128) {
        float a = ob[t];
        for (int k = 0; k < 128; k++) a += h3[k] * ow[(size_t)k * 128 + t];
        out[t] = a;
    }
}

// ---------------- launch ----------------
extern "C" void kernel_launch(void* const* d_in, const int* in_sizes, int n_in,
                              void* d_out, int out_size, void* d_ws, size_t ws_size,
                              hipStream_t stream) {
    const float* X       = (const float*)d_in[0];
    const int*   senders = (const int*)d_in[1];
    const float* lw0 = (const float*)d_in[3];
    const float* lb0 = (const float*)d_in[4];
    const float* aw0 = (const float*)d_in[5];
    const float* aq0 = (const float*)d_in[6];
    const float* lw1 = (const float*)d_in[7];
    const float* lb1 = (const float*)d_in[8];
    const float* aw1 = (const float*)d_in[9];
    const float* aq1 = (const float*)d_in[10];
    const float* lw2 = (const float*)d_in[11];
    const float* lb2 = (const float*)d_in[12];
    const float* aw2 = (const float*)d_in[13];
    const float* aq2 = (const float*)d_in[14];
    const float* owp = (const float*)d_in[15];
    const float* obp = (const float*)d_in[16];
    float* out = (float*)d_out;

    char* ws = (char*)d_ws;
    size_t off = 0;
    auto alloc = [&](size_t nbytes) -> void* {
        void* p = ws + off;
        off += (nbytes + 255) & ~(size_t)255;
        return p;
    };
    // ---- zero-initialized region (contiguous from ws start) ----
    float* lgc0 = (float*)alloc(L0PAD * 4);
    float* lgc1 = (float*)alloc(MAXL1 * 4);
    float* C0   = (float*)alloc((size_t)MAXL1 * 512 * 4);
    float* C1   = (float*)alloc((size_t)MAXL2 * 256 * 4);
    size_t zero_end = off;
    // ---- rest ----
    int* inv0  = (int*)alloc(NN * 4);
    int* inv1  = (int*)alloc(NN * 4);
    int* inv2  = (int*)alloc(NN * 4);
    int* list0 = (int*)alloc(L0PAD * 4);
    int* list1 = (int*)alloc(MAXL1 * 4);
    int* list2 = (int*)alloc(MAXL2 * 4);
    int* cnts  = (int*)alloc(4 * 4);
    ushort_t* Xg  = (ushort_t*)alloc((size_t)L0PAD * 1024 * 2);  // bf16
    ushort_t* awT = (ushort_t*)alloc((size_t)512 * 1024 * 2);    // bf16 [N][K]
    float* hN0c = (float*)alloc((size_t)MAXL1 * 1024 * 4);
    float* h1c  = (float*)alloc((size_t)MAXL1 * 512 * 4);
    float* hN1c = (float*)alloc((size_t)MAXL2 * 512 * 4);
    float* h2c  = (float*)alloc((size_t)MAXL2 * 256 * 4);
    (void)in_sizes; (void)n_in; (void)out_size; (void)ws_size;

    int nz4 = (int)(zero_end / 16);
    int nzb = (nz4 + 255) / 256;

    hipLaunchKernelGGL(k_frontier, dim3(1 + nzb), dim3(256), 0, stream,
                       senders, list2, inv2, list1, inv1, list0, inv0, cnts,
                       (float4*)ws, nz4);
    hipLaunchKernelGGL(k_prep, dim3(NWBLK + L0PAD), dim3(256), 0, stream,
                       aw0, awT, X, list0, cnts + 0, Xg);

    // ---- layer 0 (din=1024, dh=512) ----
    hipLaunchKernelGGL(k_logits_mfma, dim3(73, 512 / 64, 2), dim3(256), 0, stream,
                       Xg, awT, aq0, lgc0, cnts + 0, 1024, 512);
    hipLaunchKernelGGL(k_agg, dim3(MAXL1), dim3(256), 0, stream,
                       X, (const int*)nullptr, lgc0, inv0, senders, list1, cnts + 1, hN0c, 1024);
    hipLaunchKernelGGL(k_matmul, dim3((MAXL1 + 63) / 64, 512 / 64, 8), dim3(256), 0, stream,
                       X, hN0c, list1, (int*)nullptr, lw0, aq0, C0, cnts + 1,
                       1, 0, 1024, 1024, 512, 256);
    hipLaunchKernelGGL(k_bias_relu, dim3((MAXL1 * 512 + 255) / 256), dim3(256), 0, stream,
                       C0, lb0, h1c, cnts + 1, 9);

    // ---- layer 1 (din=512, dh=256) ----
    hipLaunchKernelGGL(k_matmul, dim3((MAXL1 + 63) / 64, 256 / 64, 2), dim3(256), 0, stream,
                       h1c, h1c, list1, (int*)nullptr, aw1, aq1, lgc1, cnts + 1,
                       0, 1, 512, 0, 256, 256);
    hipLaunchKernelGGL(k_agg, dim3(MAXL2), dim3(256), 0, stream,
                       h1c, inv1, lgc1, inv1, senders, list2, cnts + 2, hN1c, 512);
    hipLaunchKernelGGL(k_matmul, dim3(1, 256 / 64, 8), dim3(256), 0, stream,
                       h1c, hN1c, list2, inv1, lw1, aq1, C1, cnts + 2,
                       2, 0, 512, 512, 256, 128);
    hipLaunchKernelGGL(k_bias_relu, dim3((MAXL2 * 256 + 255) / 256), dim3(256), 0, stream,
                       C1, lb1, h2c, cnts + 2, 8);

    // ---- layer 2 + output (fused, single block) ----
    hipLaunchKernelGGL(k_layer2, dim3(1), dim3(256), 0, stream,
                       h2c, inv2, senders, aw2, aq2, lw2, lb2, owp, obp, cnts + 2, out);
}

// Round 6
// 284.090 us; speedup vs baseline: 3.4002x; 1.0293x over previous
//
#include <hip/hip_runtime.h>
#include <math.h>

typedef unsigned short ushort_t;
typedef __attribute__((ext_vector_type(8))) short short8;
typedef __attribute__((ext_vector_type(4))) float f32x4;

// Problem constants (fixed by setup_inputs)
#define NN    20000
#define DEG   16
constexpr int MAXL2 = 1 + DEG;            // 17
constexpr int MAXL1 = MAXL2 + MAXL2*DEG;  // 289
constexpr int MAXL0 = MAXL1*DEG;          // 4624
constexpr int L0PAD = 73 * 64;            // 4672 (guard-free MFMA tiles)
constexpr int NWBLK = 512;                // cvtW tile-blocks (16 x 32)

__device__ __forceinline__ ushort_t f2bf(float f) {
    unsigned u = __float_as_uint(f);
    return (ushort_t)((u + 0x7FFFu + ((u >> 16) & 1u)) >> 16);   // RTN-even
}

// ---------------- frontier (block 0) + workspace zero (blocks 1..) ----------------
__global__ __launch_bounds__(256)
void k_frontier(const int* __restrict__ senders,
                int* list2, int* inv2, int* list1, int* inv1,
                int* list0, int* inv0, int* list3, int* cnts, float4* zp, int n4) {
    int t = threadIdx.x;
    if (blockIdx.x > 0) {
        int i = (blockIdx.x - 1) * 256 + t;
        if (i < n4) zp[i] = make_float4(0.f, 0.f, 0.f, 0.f);
        return;
    }
    __shared__ unsigned bm[625];
    __shared__ int cnt;
    auto clear = [&]() { for (int i = t; i < 625; i += 256) bm[i] = 0u; if (t == 0) cnt = 0; };
    auto tryadd = [&](int node, int* list, int* inv) {
        unsigned bit = 1u << (node & 31);
        unsigned old = atomicOr(&bm[node >> 5], bit);
        if (!(old & bit)) { int p = atomicAdd(&cnt, 1); list[p] = node; inv[node] = p; }
    };
    clear(); __syncthreads();
    if (t < 17) { int node = (t < 16) ? senders[14 * DEG + t] : 14; tryadd(node, list2, inv2); }
    __syncthreads();
    int c2 = cnt; if (t == 0) cnts[2] = c2;
    __syncthreads(); clear(); __syncthreads();
    for (int i = t; i < c2 * 17; i += 256) {
        int r = i / 17, k = i - 17 * r;
        int node = (k < 16) ? senders[list2[r] * DEG + k] : list2[r];
        tryadd(node, list1, inv1);
    }
    __syncthreads();
    int c1 = cnt; if (t == 0) cnts[1] = c1;
    __syncthreads(); clear(); __syncthreads();
    for (int i = t; i < c1 * 16; i += 256) {
        int r = i >> 4, k = i & 15;
        tryadd(senders[list1[r] * DEG + k], list0, inv0);
    }
    __syncthreads();
    if (t == 0) { cnts[0] = cnt; cnts[3] = 1; list3[0] = 14; }  // list3 MUST be written (ws is poisoned)
}

// ---------------- fused prep: transpose aw0 -> bf16 [N][K]  +  gather X[list0] -> bf16 ----------------
__global__ __launch_bounds__(256)
void k_prep(const float* __restrict__ W, ushort_t* __restrict__ WT,
            const float* __restrict__ X, const int* __restrict__ list0,
            const int* __restrict__ cnt0, ushort_t* __restrict__ Xg) {
    int t = threadIdx.x;
    if (blockIdx.x < NWBLK) {
        // aw0 [K=1024][N=512] -> WT [512][1024]
        __shared__ float tile[32][33];
        int b = blockIdx.x;
        int bx = b & 15, by = b >> 4;
        int i0 = t >> 3, j0 = (t & 7) * 4;
        int k = by * 32 + i0, n0 = bx * 32;
        float4 v = *(const float4*)(W + (size_t)k * 512 + n0 + j0);
        tile[i0][j0] = v.x; tile[i0][j0 + 1] = v.y; tile[i0][j0 + 2] = v.z; tile[i0][j0 + 3] = v.w;
        __syncthreads();
        int n = n0 + i0, kc = j0;
        ushort_t* p = WT + (size_t)n * 1024 + by * 32 + kc;
        p[0] = f2bf(tile[kc][i0]); p[1] = f2bf(tile[kc + 1][i0]);
        p[2] = f2bf(tile[kc + 2][i0]); p[3] = f2bf(tile[kc + 3][i0]);
    } else {
        int r = blockIdx.x - NWBLK;
        int rc = *cnt0;
        ushort_t o0 = 0, o1 = 0, o2 = 0, o3 = 0;
        if (r < rc) {
            float4 v = *(const float4*)(X + (size_t)list0[r] * 1024 + t * 4);
            o0 = f2bf(v.x); o1 = f2bf(v.y); o2 = f2bf(v.z); o3 = f2bf(v.w);
        }
        ushort_t* p = Xg + (size_t)r * 1024 + t * 4;
        p[0] = o0; p[1] = o1; p[2] = o2; p[3] = o3;
    }
}

// ---------------- bf16 MFMA logits GEMM: lgc[r] += sum_c relu(Xg[r]@W)[c]*aq[c] ----------------
// NOTE: fused relu epilogue => split-K is FORBIDDEN (relu of partial sums is wrong).
__global__ __launch_bounds__(256)
void k_logits_mfma(const ushort_t* __restrict__ Xg,  // [L0PAD][K]
                   const ushort_t* __restrict__ WT,  // [NC][K]
                   const float* __restrict__ aq, float* __restrict__ lgc,
                   const int* __restrict__ cnt, int K) {
    __shared__ short As[64 * 40];
    __shared__ short Bs[64 * 40];
    int rcnt = *cnt;
    int row0 = blockIdx.x * 64;
    if (row0 >= rcnt) return;
    int col0 = blockIdx.y * 64;
    int t = threadIdx.x;
    int w = t >> 6, lane = t & 63;

    int sr = t >> 2, sk = (t & 3) * 8;
    const ushort_t* ap = Xg + (size_t)(row0 + sr) * K + sk;
    const ushort_t* bp = WT + (size_t)(col0 + sr) * K + sk;

    int fm = lane & 15, fq = lane >> 4;
    const short* arow = As + (w * 16 + fm) * 40 + fq * 8;
    const short* brow = Bs + fm * 40 + fq * 8;

    f32x4 acc0 = {0.f,0.f,0.f,0.f}, acc1 = {0.f,0.f,0.f,0.f};
    f32x4 acc2 = {0.f,0.f,0.f,0.f}, acc3 = {0.f,0.f,0.f,0.f};

    short8 pa = *(const short8*)(ap);
    short8 pb = *(const short8*)(bp);
    for (int k0 = 0; k0 < K; k0 += 32) {
        *(short8*)(As + sr * 40 + sk) = pa;
        *(short8*)(Bs + sr * 40 + sk) = pb;
        __syncthreads();
        if (k0 + 32 < K) {
            pa = *(const short8*)(ap + k0 + 32);
            pb = *(const short8*)(bp + k0 + 32);
        }
        short8 af = *(const short8*)arow;
        short8 b0 = *(const short8*)(brow);
        short8 b1 = *(const short8*)(brow + 16 * 40);
        short8 b2 = *(const short8*)(brow + 32 * 40);
        short8 b3 = *(const short8*)(brow + 48 * 40);
        acc0 = __builtin_amdgcn_mfma_f32_16x16x32_bf16(af, b0, acc0, 0, 0, 0);
        acc1 = __builtin_amdgcn_mfma_f32_16x16x32_bf16(af, b1, acc1, 0, 0, 0);
        acc2 = __builtin_amdgcn_mfma_f32_16x16x32_bf16(af, b2, acc2, 0, 0, 0);
        acc3 = __builtin_amdgcn_mfma_f32_16x16x32_bf16(af, b3, acc3, 0, 0, 0);
        __syncthreads();
    }

    float aqv0 = aq[col0 + fm], aqv1 = aq[col0 + 16 + fm];
    float aqv2 = aq[col0 + 32 + fm], aqv3 = aq[col0 + 48 + fm];
#pragma unroll
    for (int r = 0; r < 4; r++) {
        float v = fmaxf(acc0[r], 0.f) * aqv0 + fmaxf(acc1[r], 0.f) * aqv1
                + fmaxf(acc2[r], 0.f) * aqv2 + fmaxf(acc3[r], 0.f) * aqv3;
#pragma unroll
        for (int off = 1; off < 16; off <<= 1) v += __shfl_xor(v, off);
        if (fm == 0) atomicAdd(&lgc[row0 + w * 16 + fq * 4 + r], v);
    }
}

// ---------------- generic pipelined fp32 GEMM (64x64, BK=32) ----------------
// omode 0: C += acc (atomic, split-K allowed)
// omode 1: lgc[r] += sum_c relu(acc)*aq[c]  -- split-K FORBIDDEN (relu of partials)
__global__ __launch_bounds__(256)
void k_matmul(const float* __restrict__ A1, const float* __restrict__ A2,
              const int* __restrict__ list, const int* __restrict__ inv,
              const float* __restrict__ B, const float* __restrict__ aq,
              float* __restrict__ C, const int* __restrict__ cnt,
              int amode, int omode, int K1, int K2, int NC, int KS) {
    __shared__ float As[32][68];
    __shared__ float Bs[32][64];
    __shared__ float rowsum[64];

    int rcnt = *cnt;
    int row0 = blockIdx.x * 64;
    if (row0 >= rcnt) return;
    int col0 = blockIdx.y * 64;
    int K = K1 + K2;
    int kbeg = blockIdx.z * KS;
    int kend = kbeg + KS; if (kend > K) kend = K;

    int t = threadIdx.x;
    int ty = t >> 4, tx = t & 15;
    int lr = t >> 2, kaoff = (t & 3) * 4;
    int grow = row0 + lr;
    bool rowValid = grow < rcnt;
    const float* rp1 = A1;
    const float* rp2 = A2;
    if (rowValid) {
        int hrow;
        if (amode == 0) hrow = grow;
        else { int node = list[grow]; hrow = (amode == 2) ? inv[node] : node; }
        rp1 = A1 + (size_t)hrow * K1;
        rp2 = A2 + (size_t)grow * K2;
    }
    const float* Bp = B + col0;
    int bidx0 = t, bidx1 = t + 256;

    auto loadA = [&](int k) -> float4 {
        if (!rowValid) return make_float4(0.f, 0.f, 0.f, 0.f);
        const float* src = (k < K1) ? (rp1 + k) : (rp2 + (k - K1));
        return *(const float4*)src;
    };
    auto loadB = [&](int idx, int k0) -> float4 {
        int row = idx >> 4, c4 = (idx & 15) * 4;
        return *(const float4*)(Bp + (size_t)(k0 + row) * NC + c4);
    };

    float4 pa0 = loadA(kbeg + kaoff);
    float4 pa1 = loadA(kbeg + kaoff + 16);
    float4 pb0 = loadB(bidx0, kbeg);
    float4 pb1 = loadB(bidx1, kbeg);

    float acc[4][4] = {};
    for (int k0 = kbeg; k0 < kend; k0 += 32) {
        As[kaoff + 0][lr] = pa0.x; As[kaoff + 1][lr] = pa0.y;
        As[kaoff + 2][lr] = pa0.z; As[kaoff + 3][lr] = pa0.w;
        As[kaoff + 16][lr] = pa1.x; As[kaoff + 17][lr] = pa1.y;
        As[kaoff + 18][lr] = pa1.z; As[kaoff + 19][lr] = pa1.w;
        *(float4*)&Bs[bidx0 >> 4][(bidx0 & 15) * 4] = pb0;
        *(float4*)&Bs[bidx1 >> 4][(bidx1 & 15) * 4] = pb1;
        __syncthreads();
        if (k0 + 32 < kend) {
            pa0 = loadA(k0 + 32 + kaoff);
            pa1 = loadA(k0 + 32 + kaoff + 16);
            pb0 = loadB(bidx0, k0 + 32);
            pb1 = loadB(bidx1, k0 + 32);
        }
#pragma unroll
        for (int kk = 0; kk < 32; kk++) {
            float4 a4 = *(const float4*)&As[kk][ty * 4];
            float4 b4 = *(const float4*)&Bs[kk][tx * 4];
            float a[4] = {a4.x, a4.y, a4.z, a4.w};
            float b[4] = {b4.x, b4.y, b4.z, b4.w};
#pragma unroll
            for (int i = 0; i < 4; i++)
#pragma unroll
                for (int j = 0; j < 4; j++) acc[i][j] += a[i] * b[j];
        }
        __syncthreads();
    }

    if (omode == 0) {
#pragma unroll
        for (int i = 0; i < 4; i++) {
            int r = row0 + ty * 4 + i;
            if (r < rcnt) {
                float* Crow = C + (size_t)r * NC + col0 + tx * 4;
#pragma unroll
                for (int j = 0; j < 4; j++) atomicAdd(&Crow[j], acc[i][j]);
            }
        }
    } else {
        if (t < 64) rowsum[t] = 0.f;
        __syncthreads();
        float aqv[4];
#pragma unroll
        for (int j = 0; j < 4; j++) aqv[j] = aq[col0 + tx * 4 + j];
#pragma unroll
        for (int i = 0; i < 4; i++) {
            float s = 0.f;
#pragma unroll
            for (int j = 0; j < 4; j++) {
                float v = acc[i][j];
                v = v > 0.f ? v : 0.f;
                s += v * aqv[j];
            }
            atomicAdd(&rowsum[ty * 4 + i], s);
        }
        __syncthreads();
        if (t < 64) {
            int r = row0 + t;
            if (r < rcnt) atomicAdd(&C[r], rowsum[t]);
        }
    }
}

// ---------------- bias + relu epilogue ----------------
__global__ void k_bias_relu(const float* __restrict__ C, const float* __restrict__ b,
                            float* __restrict__ H, const int* __restrict__ cnt, int ncShift) {
    int rcnt = *cnt;
    int NC = 1 << ncShift;
    int e = blockIdx.x * 256 + threadIdx.x;
    int r = e >> ncShift;
    if (r >= rcnt) return;
    int c = e & (NC - 1);
    float v = C[(size_t)r * NC + c] + b[c];
    H[(size_t)r * NC + c] = v > 0.f ? v : 0.f;
}

// ---------------- attention aggregate ----------------
__global__ __launch_bounds__(256)
void k_agg(const float* __restrict__ Hsrc, const int* __restrict__ invH,
           const float* __restrict__ lgc, const int* __restrict__ invL,
           const int* __restrict__ senders,
           const int* __restrict__ listN, const int* __restrict__ cntN,
           float* __restrict__ hN, int din) {
    __shared__ int   s_row[DEG];
    __shared__ float s_w[DEG];
    __shared__ float s_scale;
    int b = blockIdx.x;
    if (b >= *cntN) return;
    int n = listN[b];
    int t = threadIdx.x;
    if (t < DEG) {
        int s = senders[n * DEG + t];
        s_row[t] = invH ? invH[s] : s;
        s_w[t] = lgc[invL ? invL[s] : s];
    }
    __syncthreads();
    if (t == 0) {
        float m = -1e30f;
        for (int k = 0; k < DEG; k++) m = fmaxf(m, s_w[k]);
        float d = 0.f;
        for (int k = 0; k < DEG; k++) { float w = expf(s_w[k] - m); s_w[k] = w; d += w; }
        s_scale = 1.f / d;
    }
    __syncthreads();
    float scale = s_scale;
    for (int dI = t; dI < din; dI += 256) {
        float acc = 0.f;
#pragma unroll
        for (int k = 0; k < DEG; k++)
            acc += s_w[k] * Hsrc[(size_t)s_row[k] * din + dI];
        hN[(size_t)b * din + dI] = acc * scale;
    }
}

// ---------------- fused h3 bias+relu + output matvec (single block, 512 thr) ----------------
__global__ __launch_bounds__(512)
void k_out(const float* __restrict__ C2, const float* __restrict__ lb2,
           const float* __restrict__ OW, const float* __restrict__ OB,
           float* __restrict__ out) {
    __shared__ float h3s[128];
    __shared__ float part[4][128];
    int t = threadIdx.x;
    if (t < 128) { float v = C2[t] + lb2[t]; h3s[t] = v > 0.f ? v : 0.f; }
    __syncthreads();
    int j = t & 127, s = t >> 7;         // 4 k-slices of 32
    float a = 0.f;
    for (int k = s * 32; k < s * 32 + 32; k++) a += h3s[k] * OW[(size_t)k * 128 + j];
    part[s][j] = a;
    __syncthreads();
    if (t < 128) out[t] = OB[t] + part[0][t] + part[1][t] + part[2][t] + part[3][t];
}

// ---------------- launch ----------------
extern "C" void kernel_launch(void* const* d_in, const int* in_sizes, int n_in,
                              void* d_out, int out_size, void* d_ws, size_t ws_size,
                              hipStream_t stream) {
    const float* X       = (const float*)d_in[0];
    const int*   senders = (const int*)d_in[1];
    const float* lw0 = (const float*)d_in[3];
    const float* lb0 = (const float*)d_in[4];
    const float* aw0 = (const float*)d_in[5];
    const float* aq0 = (const float*)d_in[6];
    const float* lw1 = (const float*)d_in[7];
    const float* lb1 = (const float*)d_in[8];
    const float* aw1 = (const float*)d_in[9];
    const float* aq1 = (const float*)d_in[10];
    const float* lw2 = (const float*)d_in[11];
    const float* lb2 = (const float*)d_in[12];
    const float* aw2 = (const float*)d_in[13];
    const float* aq2 = (const float*)d_in[14];
    const float* owp = (const float*)d_in[15];
    const float* obp = (const float*)d_in[16];
    float* out = (float*)d_out;

    char* ws = (char*)d_ws;
    size_t off = 0;
    auto alloc = [&](size_t nbytes) -> void* {
        void* p = ws + off;
        off += (nbytes + 255) & ~(size_t)255;
        return p;
    };
    // ---- zero-initialized region (contiguous from ws start) ----
    float* lgc0 = (float*)alloc(L0PAD * 4);
    float* lgc1 = (float*)alloc(MAXL1 * 4);
    float* lgc2 = (float*)alloc(MAXL2 * 4);
    float* C0   = (float*)alloc((size_t)MAXL1 * 512 * 4);
    float* C1   = (float*)alloc((size_t)MAXL2 * 256 * 4);
    float* C2   = (float*)alloc(128 * 4);
    size_t zero_end = off;
    // ---- rest ----
    int* inv0  = (int*)alloc(NN * 4);
    int* inv1  = (int*)alloc(NN * 4);
    int* inv2  = (int*)alloc(NN * 4);
    int* list0 = (int*)alloc(L0PAD * 4);
    int* list1 = (int*)alloc(MAXL1 * 4);
    int* list2 = (int*)alloc(MAXL2 * 4);
    int* list3 = (int*)alloc(4);
    int* cnts  = (int*)alloc(4 * 4);
    ushort_t* Xg  = (ushort_t*)alloc((size_t)L0PAD * 1024 * 2);  // bf16
    ushort_t* awT = (ushort_t*)alloc((size_t)512 * 1024 * 2);    // bf16 [N][K]
    float* hN0c = (float*)alloc((size_t)MAXL1 * 1024 * 4);
    float* h1c  = (float*)alloc((size_t)MAXL1 * 512 * 4);
    float* hN1c = (float*)alloc((size_t)MAXL2 * 512 * 4);
    float* h2c  = (float*)alloc((size_t)MAXL2 * 256 * 4);
    float* hN2c = (float*)alloc(256 * 4);
    (void)in_sizes; (void)n_in; (void)out_size; (void)ws_size;

    int nz4 = (int)(zero_end / 16);
    int nzb = (nz4 + 255) / 256;

    hipLaunchKernelGGL(k_frontier, dim3(1 + nzb), dim3(256), 0, stream,
                       senders, list2, inv2, list1, inv1, list0, inv0, list3, cnts,
                       (float4*)ws, nz4);
    hipLaunchKernelGGL(k_prep, dim3(NWBLK + L0PAD), dim3(256), 0, stream,
                       aw0, awT, X, list0, cnts + 0, Xg);

    // ---- layer 0 (din=1024, dh=512) ----
    hipLaunchKernelGGL(k_logits_mfma, dim3(73, 512 / 64, 1), dim3(256), 0, stream,
                       Xg, awT, aq0, lgc0, cnts + 0, 1024);
    hipLaunchKernelGGL(k_agg, dim3(MAXL1), dim3(256), 0, stream,
                       X, (const int*)nullptr, lgc0, inv0, senders, list1, cnts + 1, hN0c, 1024);
    hipLaunchKernelGGL(k_matmul, dim3((MAXL1 + 63) / 64, 512 / 64, 8), dim3(256), 0, stream,
                       X, hN0c, list1, (int*)nullptr, lw0, aq0, C0, cnts + 1,
                       1, 0, 1024, 1024, 512, 256);
    hipLaunchKernelGGL(k_bias_relu, dim3((MAXL1 * 512 + 255) / 256), dim3(256), 0, stream,
                       C0, lb0, h1c, cnts + 1, 9);

    // ---- layer 1 (din=512, dh=256) ----
    hipLaunchKernelGGL(k_matmul, dim3((MAXL1 + 63) / 64, 256 / 64, 1), dim3(256), 0, stream,
                       h1c, h1c, list1, (int*)nullptr, aw1, aq1, lgc1, cnts + 1,
                       0, 1, 512, 0, 256, 512);
    hipLaunchKernelGGL(k_agg, dim3(MAXL2), dim3(256), 0, stream,
                       h1c, inv1, lgc1, inv1, senders, list2, cnts + 2, hN1c, 512);
    hipLaunchKernelGGL(k_matmul, dim3(1, 256 / 64, 8), dim3(256), 0, stream,
                       h1c, hN1c, list2, inv1, lw1, aq1, C1, cnts + 2,
                       2, 0, 512, 512, 256, 128);
    hipLaunchKernelGGL(k_bias_relu, dim3((MAXL2 * 256 + 255) / 256), dim3(256), 0, stream,
                       C1, lb1, h2c, cnts + 2, 8);

    // ---- layer 2 (din=256, dh=128): multi-block stages ----
    hipLaunchKernelGGL(k_matmul, dim3(1, 128 / 64, 1), dim3(256), 0, stream,
                       h2c, h2c, list2, (int*)nullptr, aw2, aq2, lgc2, cnts + 2,
                       0, 1, 256, 0, 128, 256);
    hipLaunchKernelGGL(k_agg, dim3(1), dim3(256), 0, stream,
                       h2c, inv2, lgc2, inv2, senders, list3, cnts + 3, hN2c, 256);
    hipLaunchKernelGGL(k_matmul, dim3(1, 128 / 64, 4), dim3(256), 0, stream,
                       h2c, hN2c, list3, inv2, lw2, aq2, C2, cnts + 3,
                       2, 0, 256, 256, 128, 128);
    hipLaunchKernelGGL(k_out, dim3(1), dim3(512), 0, stream, C2, lb2, owp, obp, out);
}